// Round 1
// baseline (553.006 us; speedup 1.0000x reference)
//
#include <hip/hip_runtime.h>

#define NG 128
#define G3 (NG*NG*NG)
#define NSCAN_BLOCKS (G3/256)   // 8192

__device__ __constant__ const float c_DX      = 1.0f/128.0f;
__device__ __constant__ const float c_INV_DX  = 128.0f;

#define DT      1e-4f
#define P_VOL   ((1.0f/256.0f)*(1.0f/256.0f))
#define P_MASS  P_VOL
#define MU0     (5000.0f/(2.0f*1.2f))
#define LAM0    (5000.0f*0.2f/(1.2f*0.6f))

// P2G scatter tile: 4x4 grid columns x full z, 32KB LDS accumulator
#define TI 4
#define TJ 4

// 64-byte packed particle record, stored in cell-bucket order
// r0 = {A0, A1, A2, particle_id}   A = x*INV_DX (absolute grid coord; exact)
// r1 = {aff0..3}, r2 = {aff4..7}, r3 = {aff8, mv0, mv1, mv2}
struct __align__(16) PRec {
    float4 r0, r1, r2, r3;
};

// ---------------- 3x3 SVD via Jacobi on A^T A ----------------
__device__ inline void jacobi_rot(float S[3][3], float V[3][3], int p, int q) {
    float apq = S[p][q];
    if (fabsf(apq) < 1e-24f) return;
    float tau = (S[q][q] - S[p][p]) / (2.0f * apq);
    float t = copysignf(1.0f, tau) / (fabsf(tau) + sqrtf(1.0f + tau*tau));
    float c = rsqrtf(1.0f + t*t);
    float sn = t * c;
    #pragma unroll
    for (int k = 0; k < 3; ++k) {
        float Spk = S[p][k], Sqk = S[q][k];
        S[p][k] = c*Spk - sn*Sqk;
        S[q][k] = sn*Spk + c*Sqk;
    }
    #pragma unroll
    for (int k = 0; k < 3; ++k) {
        float Skp = S[k][p], Skq = S[k][q];
        S[k][p] = c*Skp - sn*Skq;
        S[k][q] = sn*Skp + c*Skq;
    }
    #pragma unroll
    for (int k = 0; k < 3; ++k) {
        float Vkp = V[k][p], Vkq = V[k][q];
        V[k][p] = c*Vkp - sn*Vkq;
        V[k][q] = sn*Vkp + c*Vkq;
    }
}

__device__ inline void svd3(const float A[9], float U[9], float sv[3], float V[9]) {
    float S[3][3];
    #pragma unroll
    for (int i = 0; i < 3; ++i)
        #pragma unroll
        for (int j = 0; j < 3; ++j) {
            float acc = 0.f;
            #pragma unroll
            for (int k = 0; k < 3; ++k) acc += A[k*3+i]*A[k*3+j];
            S[i][j] = acc;
        }
    float Vm[3][3] = {{1.f,0.f,0.f},{0.f,1.f,0.f},{0.f,0.f,1.f}};
    #pragma unroll
    for (int sweep = 0; sweep < 4; ++sweep) {
        jacobi_rot(S, Vm, 0, 1);
        jacobi_rot(S, Vm, 0, 2);
        jacobi_rot(S, Vm, 1, 2);
    }
    float lam[3] = {S[0][0], S[1][1], S[2][2]};
    int i0 = 0, i1 = 1, i2 = 2, t;
    if (lam[i0] < lam[i1]) { t = i0; i0 = i1; i1 = t; }
    if (lam[i0] < lam[i2]) { t = i0; i0 = i2; i2 = t; }
    if (lam[i1] < lam[i2]) { t = i1; i1 = i2; i2 = t; }
    int ord[3] = {i0, i1, i2};
    #pragma unroll
    for (int c = 0; c < 3; ++c) {
        int s_ = ord[c];
        float l = fmaxf(lam[s_], 0.f);
        float sval = sqrtf(l);
        sv[c] = sval;
        float v0 = Vm[0][s_], v1 = Vm[1][s_], v2 = Vm[2][s_];
        V[0*3+c] = v0; V[1*3+c] = v1; V[2*3+c] = v2;
        float inv = (sval > 1e-12f) ? 1.0f/sval : 0.f;
        U[0*3+c] = (A[0]*v0 + A[1]*v1 + A[2]*v2)*inv;
        U[1*3+c] = (A[3]*v0 + A[4]*v1 + A[5]*v2)*inv;
        U[2*3+c] = (A[6]*v0 + A[7]*v1 + A[8]*v2)*inv;
    }
}

// ---------------- binning helpers ----------------
// from absolute grid coord A: base cell + frac (all fp-exact)
__device__ inline void base_from_A(float A0, float A1, float A2,
                                   int& bi, int& bj, int& bk,
                                   float& fx0, float& fx1, float& fx2) {
    float bxf = floorf(A0 - 0.5f);
    float byf = floorf(A1 - 0.5f);
    float bzf = floorf(A2 - 0.5f);
    bi = (int)bxf; bj = (int)byf; bk = (int)bzf;
    bi = min(max(bi, 0), NG-3); bj = min(max(bj, 0), NG-3); bk = min(max(bk, 0), NG-3);
    fx0 = A0 - bxf;
    fx1 = A1 - byf;
    fx2 = A2 - bzf;
}

// count + per-particle rank within its cell (atomicAdd's return value)
__global__ void __launch_bounds__(256)
count_kernel(const float* __restrict__ x, int* __restrict__ cell_count,
             int* __restrict__ rank, int N) {
    int n = blockIdx.x*256 + threadIdx.x;
    if (n >= N) return;
    int bi, bj, bk; float f0, f1, f2;
    base_from_A(x[3*n+0]*c_INV_DX, x[3*n+1]*c_INV_DX, x[3*n+2]*c_INV_DX,
                bi, bj, bk, f0, f1, f2);
    rank[n] = atomicAdd(&cell_count[(bi*NG + bj)*NG + bk], 1);
}

// ---- scan stage A: per-block (256 elems) reduction -> partial[block] ----
__global__ void __launch_bounds__(256)
scan_partial_kernel(const int* __restrict__ count, int* __restrict__ partial) {
    __shared__ int red[256];
    int t = threadIdx.x;
    red[t] = count[blockIdx.x*256 + t];
    __syncthreads();
    for (int off = 128; off > 0; off >>= 1) {
        if (t < off) red[t] += red[t+off];
        __syncthreads();
    }
    if (t == 0) partial[blockIdx.x] = red[0];
}

// ---- scan stage B: exclusive scan of 8192 partials, 1 block, 256x32 ----
__global__ void __launch_bounds__(256)
scan_partials_kernel(int* __restrict__ partial) {
    __shared__ int part[256];
    int t = threadIdx.x;
    int base = t*32;
    int local[32];
    int s = 0;
    #pragma unroll
    for (int i = 0; i < 32; ++i) { local[i] = s; s += partial[base+i]; }
    part[t] = s;
    __syncthreads();
    for (int off = 1; off < 256; off <<= 1) {
        int v = (t >= off) ? part[t-off] : 0;
        __syncthreads();
        part[t] += v;
        __syncthreads();
    }
    int prev = (t == 0) ? 0 : part[t-1];
    #pragma unroll
    for (int i = 0; i < 32; ++i) partial[base+i] = prev + local[i];
}

// ---- scan stage C: block-level exclusive scan + partial base -> offset ----
__global__ void __launch_bounds__(256)
scan_final_kernel(const int* __restrict__ count, const int* __restrict__ partial,
                  int* __restrict__ offset) {
    __shared__ int part[256];
    int t = threadIdx.x;
    int i = blockIdx.x*256 + t;
    int c = count[i];
    part[t] = c;
    __syncthreads();
    for (int off = 1; off < 256; off <<= 1) {
        int v = (t >= off) ? part[t-off] : 0;
        __syncthreads();
        part[t] += v;
        __syncthreads();
    }
    int base = partial[blockIdx.x];
    offset[i] = base + part[t] - c;
    if (i == G3-1) offset[G3] = base + part[t];
}

// ---------------- pre-pass: all per-particle math, coalesced reads ----------------
__global__ void __launch_bounds__(256)
pre_kernel(const float* __restrict__ x, const float* __restrict__ v,
           const float* __restrict__ Cin, const float* __restrict__ Fin,
           const float* __restrict__ Jp_in, const int* __restrict__ material,
           const int* __restrict__ offset, const int* __restrict__ rank,
           PRec* __restrict__ rec, float* __restrict__ out, int N) {
    int n = blockIdx.x*256 + threadIdx.x;
    if (n >= N) return;

    float A0 = x[3*n+0]*c_INV_DX, A1 = x[3*n+1]*c_INV_DX, A2 = x[3*n+2]*c_INV_DX;
    int bi, bj, bk; float f0, f1, f2;
    base_from_A(A0, A1, A2, bi, bj, bk, f0, f1, f2);

    float Cm[9], Fm[9];
    #pragma unroll
    for (int i = 0; i < 9; ++i) { Cm[i] = Cin[9*n+i]; Fm[i] = Fin[9*n+i]; }

    // Fn = (I + DT*C) @ F
    float Fn[9];
    #pragma unroll
    for (int i = 0; i < 3; ++i)
        #pragma unroll
        for (int k = 0; k < 3; ++k) {
            float acc = Fm[i*3+k];
            #pragma unroll
            for (int j = 0; j < 3; ++j) acc += DT * Cm[i*3+j] * Fm[j*3+k];
            Fn[i*3+k] = acc;
        }

    float Jp = Jp_in[n];
    int mat = material[n];
    float h = expf(10.0f*(1.0f - Jp));
    h = fminf(fmaxf(h, 0.1f), 5.0f);
    if (mat == 1) h = 0.3f;
    float mu = (mat == 0) ? 0.0f : MU0*h;
    float la = LAM0*h;

    float U[9], V[9], sv[3];
    svd3(Fn, U, sv, V);

    float J = 1.0f;
    float sig[3];
    #pragma unroll
    for (int d = 0; d < 2; ++d) {
        float s = sv[d];
        float ns = (mat == 2) ? fminf(fmaxf(s, 1.0f-0.025f), 1.0f+0.0045f) : s;
        Jp = Jp * s / ns;
        sig[d] = ns;
        J *= ns;
    }
    sig[2] = sv[2];

    if (mat == 0) {
        float sj = sqrtf(J);
        Fn[0]=sj; Fn[1]=0; Fn[2]=0; Fn[3]=0; Fn[4]=sj; Fn[5]=0; Fn[6]=0; Fn[7]=0; Fn[8]=sj;
    } else if (mat == 2) {
        #pragma unroll
        for (int i = 0; i < 3; ++i)
            #pragma unroll
            for (int k = 0; k < 3; ++k) {
                float acc = 0.f;
                #pragma unroll
                for (int j = 0; j < 3; ++j) acc += U[i*3+j]*sig[j]*V[k*3+j];
                Fn[i*3+k] = acc;
            }
    }

    float R[9];
    #pragma unroll
    for (int i = 0; i < 3; ++i)
        #pragma unroll
        for (int k = 0; k < 3; ++k) {
            float acc = 0.f;
            #pragma unroll
            for (int j = 0; j < 3; ++j) acc += U[i*3+j]*V[k*3+j];
            R[i*3+k] = acc;
        }

    float press = la * J * (J - 1.0f);
    float scale = -DT * P_VOL * 4.0f * c_INV_DX * c_INV_DX;
    float aff[9];
    #pragma unroll
    for (int i = 0; i < 3; ++i)
        #pragma unroll
        for (int k = 0; k < 3; ++k) {
            float acc = 0.f;
            #pragma unroll
            for (int j = 0; j < 3; ++j) acc += (Fn[i*3+j]-R[i*3+j])*Fn[k*3+j];
            acc = 2.0f*mu*acc;
            if (i == k) acc += press;
            aff[i*3+k] = scale*acc + P_MASS*Cm[i*3+k];
        }

    float* po = out + (size_t)n*25;
    po[6] = Jp;
    #pragma unroll
    for (int i = 0; i < 9; ++i) po[7+i] = Fn[i];

    // cell-bucket slot (rank captured by count_kernel's atomicAdd)
    int cell = (bi*NG + bj)*NG + bk;
    int pos = offset[cell] + rank[n];

    float4* rp = (float4*)&rec[pos];
    rp[0] = make_float4(A0, A1, A2, __int_as_float(n));
    rp[1] = make_float4(aff[0], aff[1], aff[2], aff[3]);
    rp[2] = make_float4(aff[4], aff[5], aff[6], aff[7]);
    rp[3] = make_float4(aff[8], P_MASS*v[3*n+0], P_MASS*v[3*n+1], P_MASS*v[3*n+2]);
}

// ------- fused P2G-scatter + grid update: one block per 4x4-column tile ----------
// Tile = [gi0..gi0+3] x [gj0..gj0+3] x full z(128). LDS accumulator 32KB.
// Particles needed = buckets bi in [gi0-2,gi0+3], bj in [gj0-2,gj0+3], all z.
// For fixed bi that is ONE contiguous rec[] range (cell idx = (bi*NG+bj)*NG+bk),
// so the block streams 6 coalesced ranges with uniform trip counts (no per-lane
// bucket-loop divergence), scatters the 27-cell stencil via LDS float atomics,
// then finalizes+writes its 2048 grid cells coalesced.
__global__ void __launch_bounds__(256)
p2g_scatter_kernel(const PRec* __restrict__ rec, const int* __restrict__ offset,
                   float4* __restrict__ grid, const float* __restrict__ gravity,
                   const float* __restrict__ attr_s, const float* __restrict__ attr_p) {
    __shared__ float4 acc4[TI*TJ*NG];
    float* acc = (float*)acc4;

    int t = threadIdx.x;
    int gi0 = (int)(blockIdx.x >> 5) * TI;
    int gj0 = (int)(blockIdx.x & 31) * TJ;

    int bi_lo = max(gi0-2, 0), bi_hi = min(gi0+TI-1, NG-3);
    int bj_lo = max(gj0-2, 0), bj_hi = min(gj0+TJ-1, NG-3);

    // tile-granular empty skip (uniform branch; offsets are uniform s_loads)
    int total = 0;
    for (int bi = bi_lo; bi <= bi_hi; ++bi)
        total += offset[(bi*NG + bj_hi)*NG + NG] - offset[(bi*NG + bj_lo)*NG];
    // tiles with zero particles are never read by g2p: any cell g2p touches is
    // within 1 cell of a particle base, and that particle lies in this halo.
    if (total == 0) return;

    #pragma unroll
    for (int i = 0; i < (TI*TJ*NG)/256; ++i)
        acc4[t + i*256] = make_float4(0.f, 0.f, 0.f, 0.f);
    __syncthreads();

    for (int bi = bi_lo; bi <= bi_hi; ++bi) {
        int s = offset[(bi*NG + bj_lo)*NG];
        int e = offset[(bi*NG + bj_hi)*NG + NG];
        for (int p = s + t; p < e; p += 256) {
            const float4* rp = (const float4*)&rec[p];
            float4 r0 = rp[0];
            float4 r1 = rp[1];
            float4 r2 = rp[2];
            float4 r3 = rp[3];

            int pbi, pbj, pbk; float f0, f1, f2;
            base_from_A(r0.x, r0.y, r0.z, pbi, pbj, pbk, f0, f1, f2);

            // quadratic B-spline weights, identical formulas to reference
            float wx[3], wy[3];
            wx[0] = 0.5f*(1.5f-f0)*(1.5f-f0);
            wx[1] = 0.75f-(f0-1.f)*(f0-1.f);
            wx[2] = 0.5f*(f0-0.5f)*(f0-0.5f);
            wy[0] = 0.5f*(1.5f-f1)*(1.5f-f1);
            wy[1] = 0.75f-(f1-1.f)*(f1-1.f);
            wy[2] = 0.5f*(f1-0.5f)*(f1-0.5f);

            // dpos = (offset - fx)*DX, fp-identical to reference
            float dpx[3] = {(0.f-f0)*c_DX, (1.f-f0)*c_DX, (2.f-f0)*c_DX};
            float dpy[3] = {(0.f-f1)*c_DX, (1.f-f1)*c_DX, (2.f-f1)*c_DX};
            float dpz[3] = {(0.f-f2)*c_DX, (1.f-f2)*c_DX, (2.f-f2)*c_DX};

            int li = pbi - gi0;   // uniform per row (all particles share bi)
            int lj = pbj - gj0;

            #pragma unroll
            for (int di = 0; di < 3; ++di) {
                int ci = li + di;
                if ((unsigned)ci >= TI) continue;
                #pragma unroll
                for (int dj = 0; dj < 3; ++dj) {
                    int cj = lj + dj;
                    if ((unsigned)cj >= TJ) continue;
                    // reference weight uses x,y components only (no wz)
                    float w2 = wx[di]*wy[dj];
                    float wm = w2 * P_MASS;
                    float bx = r3.y + r1.x*dpx[di] + r1.y*dpy[dj];
                    float by = r3.z + r1.w*dpx[di] + r2.x*dpy[dj];
                    float bz = r3.w + r2.z*dpx[di] + r2.w*dpy[dj];
                    int bidx = ((ci*TJ + cj)*NG + pbk)*4;
                    #pragma unroll
                    for (int dk = 0; dk < 3; ++dk) {
                        float dz = dpz[dk];
                        atomicAdd(&acc[bidx + 4*dk + 0], w2*(bx + r1.z*dz));
                        atomicAdd(&acc[bidx + 4*dk + 1], w2*(by + r2.y*dz));
                        atomicAdd(&acc[bidx + 4*dk + 2], w2*(bz + r3.x*dz));
                        atomicAdd(&acc[bidx + 4*dk + 3], wm);
                    }
                }
            }
        }
    }
    __syncthreads();

    // ---- grid update + coalesced write (z fastest within each column) ----
    float gx = DT*gravity[0]*30.0f, gy = DT*gravity[1]*30.0f, gz = DT*gravity[2]*30.0f;
    float apx = attr_p[0], apy = attr_p[1], apz = attr_p[2];
    float as  = attr_s[0] * DT * 100.0f;

    #pragma unroll
    for (int it = 0; it < (TI*TJ*NG)/256; ++it) {
        int cidx = t + it*256;
        int lz   = cidx & (NG-1);
        int pair = cidx >> 7;           // li*TJ + lj
        int lj   = pair & (TJ-1);
        int li   = pair >> 2;
        int gi = gi0 + li, gj = gj0 + lj, gk = lz;

        float4 a4 = acc4[cidx];
        float m = a4.w;
        float gvx = 0.f, gvy = 0.f, gvz = 0.f;
        if (m > 0.f) {
            float inv = 1.0f/m;
            gvx = a4.x*inv + gx; gvy = a4.y*inv + gy; gvz = a4.z*inv + gz;
            float dx_ = apx - c_DX*(float)gi;
            float dy_ = apy - c_DX*(float)gj;
            float dz_ = apz - c_DX*(float)gk;
            float nrm = sqrtf(dx_*dx_ + dy_*dy_ + dz_*dz_);
            float sc = as / (0.01f + nrm);
            gvx += dx_*sc; gvy += dy_*sc; gvz += dz_*sc;
            if (gi < 3      && gvx < 0.f) gvx = 0.f;
            if (gi > NG-3   && gvx > 0.f) gvx = 0.f;
            if (gj < 3      && gvy < 0.f) gvy = 0.f;
            if (gj > NG-3   && gvy > 0.f) gvy = 0.f;
            // z unconstrained (matches reference)
        }
        grid[(gi*NG + gj)*NG + gk] = make_float4(gvx, gvy, gvz, m);
    }
}

// ---------------- G2P (cell-sorted order, coalesced record reads) ----------------
__global__ void __launch_bounds__(256)
g2p_kernel(const PRec* __restrict__ rec, const float4* __restrict__ grid,
           float* __restrict__ out, int N) {
    int gid = blockIdx.x * 256 + threadIdx.x;
    if (gid >= N) return;

    float4 r0 = rec[gid].r0;
    float A0 = r0.x, A1 = r0.y, A2 = r0.z;
    int n = __float_as_int(r0.w);

    int bi, bj, bk; float fx0, fx1, fx2;
    base_from_A(A0, A1, A2, bi, bj, bk, fx0, fx1, fx2);

    float wx[3], wy[3];
    wx[0] = 0.5f*(1.5f-fx0)*(1.5f-fx0); wx[1] = 0.75f-(fx0-1.f)*(fx0-1.f); wx[2] = 0.5f*(fx0-0.5f)*(fx0-0.5f);
    wy[0] = 0.5f*(1.5f-fx1)*(1.5f-fx1); wy[1] = 0.75f-(fx1-1.f)*(fx1-1.f); wy[2] = 0.5f*(fx1-0.5f)*(fx1-0.5f);

    float nvx = 0.f, nvy = 0.f, nvz = 0.f;
    float nC[9];
    #pragma unroll
    for (int i = 0; i < 9; ++i) nC[i] = 0.f;

    #pragma unroll
    for (int i = 0; i < 3; ++i) {
        float dpx = (float)i - fx0;
        #pragma unroll
        for (int j = 0; j < 3; ++j) {
            float wgt = wx[i]*wy[j];
            float dpy = (float)j - fx1;
            int cell0 = ((bi+i)*NG + (bj+j))*NG + bk;
            #pragma unroll
            for (int k = 0; k < 3; ++k) {
                float dpz = (float)k - fx2;
                float4 gv = grid[cell0 + k];
                float wgx = wgt*gv.x, wgy = wgt*gv.y, wgz = wgt*gv.z;
                nvx += wgx; nvy += wgy; nvz += wgz;
                nC[0] += wgx*dpx; nC[1] += wgx*dpy; nC[2] += wgx*dpz;
                nC[3] += wgy*dpx; nC[4] += wgy*dpy; nC[5] += wgy*dpz;
                nC[6] += wgz*dpx; nC[7] += wgz*dpy; nC[8] += wgz*dpz;
            }
        }
    }

    float* po = out + (size_t)n*25;
    float px = A0*c_DX, py = A1*c_DX, pz = A2*c_DX;   // exact reconstruction
    po[0] = px + DT*nvx;
    po[1] = py + DT*nvy;
    po[2] = pz + DT*nvz;
    po[3] = nvx; po[4] = nvy; po[5] = nvz;
    float s4 = 4.0f*c_INV_DX;
    #pragma unroll
    for (int i = 0; i < 9; ++i) po[16+i] = s4*nC[i];
}

extern "C" void kernel_launch(void* const* d_in, const int* in_sizes, int n_in,
                              void* d_out, int out_size, void* d_ws, size_t ws_size,
                              hipStream_t stream) {
    const float* x        = (const float*)d_in[0];
    const float* v        = (const float*)d_in[1];
    const float* C        = (const float*)d_in[2];
    const float* F        = (const float*)d_in[3];
    const float* Jp       = (const float*)d_in[4];
    const float* gravity  = (const float*)d_in[5];
    const float* attr_s   = (const float*)d_in[6];
    const float* attr_p   = (const float*)d_in[7];
    const int*   material = (const int*)d_in[8];
    float* out = (float*)d_out;
    int N = in_sizes[0] / 3;

    // workspace: [count G3] (zeroed) [offset G3+1][partial][rank N][grid][rec]
    char* ws = (char*)d_ws;
    size_t o = 0;
    int* cell_count = (int*)(ws + o);      o += (size_t)G3*sizeof(int);
    size_t zero_bytes = o;
    int* offset     = (int*)(ws + o);      o += ((size_t)G3+1)*sizeof(int);
    int* partial    = (int*)(ws + o);      o += (size_t)NSCAN_BLOCKS*sizeof(int);
    int* rank       = (int*)(ws + o);      o += (size_t)N*sizeof(int);
    o = (o + 127) & ~(size_t)127;
    float4* grid    = (float4*)(ws + o);   o += (size_t)G3*sizeof(float4);
    PRec* rec       = (PRec*)(ws + o);     o += (size_t)N*sizeof(PRec);

    hipMemsetAsync(d_ws, 0, zero_bytes, stream);

    int pblocks = (N + 255) / 256;
    count_kernel<<<pblocks, 256, 0, stream>>>(x, cell_count, rank, N);
    scan_partial_kernel<<<NSCAN_BLOCKS, 256, 0, stream>>>(cell_count, partial);
    scan_partials_kernel<<<1, 256, 0, stream>>>(partial);
    scan_final_kernel<<<NSCAN_BLOCKS, 256, 0, stream>>>(cell_count, partial, offset);
    pre_kernel<<<pblocks, 256, 0, stream>>>(x, v, C, F, Jp, material,
                                            offset, rank, rec, out, N);
    p2g_scatter_kernel<<<(NG/TI)*(NG/TJ), 256, 0, stream>>>(rec, offset, grid,
                                                            gravity, attr_s, attr_p);
    g2p_kernel<<<pblocks, 256, 0, stream>>>(rec, grid, out, N);
}

// Round 2
// 282.223 us; speedup vs baseline: 1.9595x; 1.9595x over previous
//
#include <hip/hip_runtime.h>

#define NG 128
#define G3 (NG*NG*NG)
#define NSCAN_BLOCKS (G3/256)   // 8192

__device__ __constant__ const float c_DX      = 1.0f/128.0f;
__device__ __constant__ const float c_INV_DX  = 128.0f;

#define DT      1e-4f
#define P_VOL   ((1.0f/256.0f)*(1.0f/256.0f))
#define P_MASS  P_VOL
#define MU0     (5000.0f/(2.0f*1.2f))
#define LAM0    (5000.0f*0.2f/(1.2f*0.6f))

// 64-byte packed particle record, stored in cell-bucket order
// r0 = {A0, A1, A2, particle_id}   A = x*INV_DX (absolute grid coord; exact)
// r1 = {aff0..3}, r2 = {aff4..7}, r3 = {aff8, mv0, mv1, mv2}
struct __align__(16) PRec {
    float4 r0, r1, r2, r3;
};

// ---------------- 3x3 SVD via Jacobi on A^T A ----------------
__device__ inline void jacobi_rot(float S[3][3], float V[3][3], int p, int q) {
    float apq = S[p][q];
    if (fabsf(apq) < 1e-24f) return;
    float tau = (S[q][q] - S[p][p]) / (2.0f * apq);
    float t = copysignf(1.0f, tau) / (fabsf(tau) + sqrtf(1.0f + tau*tau));
    float c = rsqrtf(1.0f + t*t);
    float sn = t * c;
    #pragma unroll
    for (int k = 0; k < 3; ++k) {
        float Spk = S[p][k], Sqk = S[q][k];
        S[p][k] = c*Spk - sn*Sqk;
        S[q][k] = sn*Spk + c*Sqk;
    }
    #pragma unroll
    for (int k = 0; k < 3; ++k) {
        float Skp = S[k][p], Skq = S[k][q];
        S[k][p] = c*Skp - sn*Skq;
        S[k][q] = sn*Skp + c*Skq;
    }
    #pragma unroll
    for (int k = 0; k < 3; ++k) {
        float Vkp = V[k][p], Vkq = V[k][q];
        V[k][p] = c*Vkp - sn*Vkq;
        V[k][q] = sn*Vkp + c*Vkq;
    }
}

__device__ inline void svd3(const float A[9], float U[9], float sv[3], float V[9]) {
    float S[3][3];
    #pragma unroll
    for (int i = 0; i < 3; ++i)
        #pragma unroll
        for (int j = 0; j < 3; ++j) {
            float acc = 0.f;
            #pragma unroll
            for (int k = 0; k < 3; ++k) acc += A[k*3+i]*A[k*3+j];
            S[i][j] = acc;
        }
    float Vm[3][3] = {{1.f,0.f,0.f},{0.f,1.f,0.f},{0.f,0.f,1.f}};
    #pragma unroll
    for (int sweep = 0; sweep < 4; ++sweep) {
        jacobi_rot(S, Vm, 0, 1);
        jacobi_rot(S, Vm, 0, 2);
        jacobi_rot(S, Vm, 1, 2);
    }
    float lam[3] = {S[0][0], S[1][1], S[2][2]};
    int i0 = 0, i1 = 1, i2 = 2, t;
    if (lam[i0] < lam[i1]) { t = i0; i0 = i1; i1 = t; }
    if (lam[i0] < lam[i2]) { t = i0; i0 = i2; i2 = t; }
    if (lam[i1] < lam[i2]) { t = i1; i1 = i2; i2 = t; }
    int ord[3] = {i0, i1, i2};
    #pragma unroll
    for (int c = 0; c < 3; ++c) {
        int s_ = ord[c];
        float l = fmaxf(lam[s_], 0.f);
        float sval = sqrtf(l);
        sv[c] = sval;
        float v0 = Vm[0][s_], v1 = Vm[1][s_], v2 = Vm[2][s_];
        V[0*3+c] = v0; V[1*3+c] = v1; V[2*3+c] = v2;
        float inv = (sval > 1e-12f) ? 1.0f/sval : 0.f;
        U[0*3+c] = (A[0]*v0 + A[1]*v1 + A[2]*v2)*inv;
        U[1*3+c] = (A[3]*v0 + A[4]*v1 + A[5]*v2)*inv;
        U[2*3+c] = (A[6]*v0 + A[7]*v1 + A[8]*v2)*inv;
    }
}

// ---------------- binning helpers ----------------
// from absolute grid coord A: base cell + frac (all fp-exact)
__device__ inline void base_from_A(float A0, float A1, float A2,
                                   int& bi, int& bj, int& bk,
                                   float& fx0, float& fx1, float& fx2) {
    float bxf = floorf(A0 - 0.5f);
    float byf = floorf(A1 - 0.5f);
    float bzf = floorf(A2 - 0.5f);
    bi = (int)bxf; bj = (int)byf; bk = (int)bzf;
    bi = min(max(bi, 0), NG-3); bj = min(max(bj, 0), NG-3); bk = min(max(bk, 0), NG-3);
    fx0 = A0 - bxf;
    fx1 = A1 - byf;
    fx2 = A2 - bzf;
}

// count + per-particle rank within its cell (atomicAdd's return value)
__global__ void __launch_bounds__(256)
count_kernel(const float* __restrict__ x, int* __restrict__ cell_count,
             int* __restrict__ rank, int N) {
    int n = blockIdx.x*256 + threadIdx.x;
    if (n >= N) return;
    int bi, bj, bk; float f0, f1, f2;
    base_from_A(x[3*n+0]*c_INV_DX, x[3*n+1]*c_INV_DX, x[3*n+2]*c_INV_DX,
                bi, bj, bk, f0, f1, f2);
    rank[n] = atomicAdd(&cell_count[(bi*NG + bj)*NG + bk], 1);
}

// ---- scan stage A: per-block (256 elems) reduction -> partial[block] ----
__global__ void __launch_bounds__(256)
scan_partial_kernel(const int* __restrict__ count, int* __restrict__ partial) {
    __shared__ int red[256];
    int t = threadIdx.x;
    red[t] = count[blockIdx.x*256 + t];
    __syncthreads();
    for (int off = 128; off > 0; off >>= 1) {
        if (t < off) red[t] += red[t+off];
        __syncthreads();
    }
    if (t == 0) partial[blockIdx.x] = red[0];
}

// ---- scan stage B: exclusive scan of 8192 partials, 1 block, 256x32 ----
__global__ void __launch_bounds__(256)
scan_partials_kernel(int* __restrict__ partial) {
    __shared__ int part[256];
    int t = threadIdx.x;
    int base = t*32;
    int local[32];
    int s = 0;
    #pragma unroll
    for (int i = 0; i < 32; ++i) { local[i] = s; s += partial[base+i]; }
    part[t] = s;
    __syncthreads();
    for (int off = 1; off < 256; off <<= 1) {
        int v = (t >= off) ? part[t-off] : 0;
        __syncthreads();
        part[t] += v;
        __syncthreads();
    }
    int prev = (t == 0) ? 0 : part[t-1];
    #pragma unroll
    for (int i = 0; i < 32; ++i) partial[base+i] = prev + local[i];
}

// ---- scan stage C: block-level exclusive scan + partial base -> offset ----
__global__ void __launch_bounds__(256)
scan_final_kernel(const int* __restrict__ count, const int* __restrict__ partial,
                  int* __restrict__ offset) {
    __shared__ int part[256];
    int t = threadIdx.x;
    int i = blockIdx.x*256 + t;
    int c = count[i];
    part[t] = c;
    __syncthreads();
    for (int off = 1; off < 256; off <<= 1) {
        int v = (t >= off) ? part[t-off] : 0;
        __syncthreads();
        part[t] += v;
        __syncthreads();
    }
    int base = partial[blockIdx.x];
    offset[i] = base + part[t] - c;
    if (i == G3-1) offset[G3] = base + part[t];
}

// ---------------- pre-pass: all per-particle math, coalesced reads ----------------
__global__ void __launch_bounds__(256)
pre_kernel(const float* __restrict__ x, const float* __restrict__ v,
           const float* __restrict__ Cin, const float* __restrict__ Fin,
           const float* __restrict__ Jp_in, const int* __restrict__ material,
           const int* __restrict__ offset, const int* __restrict__ rank,
           PRec* __restrict__ rec, float* __restrict__ out, int N) {
    int n = blockIdx.x*256 + threadIdx.x;
    if (n >= N) return;

    float A0 = x[3*n+0]*c_INV_DX, A1 = x[3*n+1]*c_INV_DX, A2 = x[3*n+2]*c_INV_DX;
    int bi, bj, bk; float f0, f1, f2;
    base_from_A(A0, A1, A2, bi, bj, bk, f0, f1, f2);

    float Cm[9], Fm[9];
    #pragma unroll
    for (int i = 0; i < 9; ++i) { Cm[i] = Cin[9*n+i]; Fm[i] = Fin[9*n+i]; }

    // Fn = (I + DT*C) @ F
    float Fn[9];
    #pragma unroll
    for (int i = 0; i < 3; ++i)
        #pragma unroll
        for (int k = 0; k < 3; ++k) {
            float acc = Fm[i*3+k];
            #pragma unroll
            for (int j = 0; j < 3; ++j) acc += DT * Cm[i*3+j] * Fm[j*3+k];
            Fn[i*3+k] = acc;
        }

    float Jp = Jp_in[n];
    int mat = material[n];
    float h = expf(10.0f*(1.0f - Jp));
    h = fminf(fmaxf(h, 0.1f), 5.0f);
    if (mat == 1) h = 0.3f;
    float mu = (mat == 0) ? 0.0f : MU0*h;
    float la = LAM0*h;

    float U[9], V[9], sv[3];
    svd3(Fn, U, sv, V);

    float J = 1.0f;
    float sig[3];
    #pragma unroll
    for (int d = 0; d < 2; ++d) {
        float s = sv[d];
        float ns = (mat == 2) ? fminf(fmaxf(s, 1.0f-0.025f), 1.0f+0.0045f) : s;
        Jp = Jp * s / ns;
        sig[d] = ns;
        J *= ns;
    }
    sig[2] = sv[2];

    if (mat == 0) {
        float sj = sqrtf(J);
        Fn[0]=sj; Fn[1]=0; Fn[2]=0; Fn[3]=0; Fn[4]=sj; Fn[5]=0; Fn[6]=0; Fn[7]=0; Fn[8]=sj;
    } else if (mat == 2) {
        #pragma unroll
        for (int i = 0; i < 3; ++i)
            #pragma unroll
            for (int k = 0; k < 3; ++k) {
                float acc = 0.f;
                #pragma unroll
                for (int j = 0; j < 3; ++j) acc += U[i*3+j]*sig[j]*V[k*3+j];
                Fn[i*3+k] = acc;
            }
    }

    float R[9];
    #pragma unroll
    for (int i = 0; i < 3; ++i)
        #pragma unroll
        for (int k = 0; k < 3; ++k) {
            float acc = 0.f;
            #pragma unroll
            for (int j = 0; j < 3; ++j) acc += U[i*3+j]*V[k*3+j];
            R[i*3+k] = acc;
        }

    float press = la * J * (J - 1.0f);
    float scale = -DT * P_VOL * 4.0f * c_INV_DX * c_INV_DX;
    float aff[9];
    #pragma unroll
    for (int i = 0; i < 3; ++i)
        #pragma unroll
        for (int k = 0; k < 3; ++k) {
            float acc = 0.f;
            #pragma unroll
            for (int j = 0; j < 3; ++j) acc += (Fn[i*3+j]-R[i*3+j])*Fn[k*3+j];
            acc = 2.0f*mu*acc;
            if (i == k) acc += press;
            aff[i*3+k] = scale*acc + P_MASS*Cm[i*3+k];
        }

    float* po = out + (size_t)n*25;
    po[6] = Jp;
    #pragma unroll
    for (int i = 0; i < 9; ++i) po[7+i] = Fn[i];

    // cell-bucket slot (rank captured by count_kernel's atomicAdd)
    int cell = (bi*NG + bj)*NG + bk;
    int pos = offset[cell] + rank[n];

    float4* rp = (float4*)&rec[pos];
    rp[0] = make_float4(A0, A1, A2, __int_as_float(n));
    rp[1] = make_float4(aff[0], aff[1], aff[2], aff[3]);
    rp[2] = make_float4(aff[4], aff[5], aff[6], aff[7]);
    rp[3] = make_float4(aff[8], P_MASS*v[3*n+0], P_MASS*v[3*n+1], P_MASS*v[3*n+2]);
}

// ------- fused P2G-gather + grid update: one thread per 4 z-cells, NO atomics ----
// v2: (a) all 9 column ranges prefetched up-front (18 independent loads in
//     flight, removes per-column serial offset->loop dependency);
// (b) particle loop unrolled 2-wide: both 64B records' loads issue before
//     either body computes (2x MLP). Tail uses a zero-weight re-read of p.
__global__ void __launch_bounds__(256)
grid_gather_kernel(const PRec* __restrict__ rec, const int* __restrict__ offset,
                   float4* __restrict__ grid, const float* __restrict__ gravity,
                   const float* __restrict__ attr_s, const float* __restrict__ attr_p) {
    int g4 = blockIdx.x*256 + threadIdx.x;   // quad index (G3/4 total)
    int zq = g4 & 31;
    int gj = (g4 >> 5) & (NG-1);
    int gi = g4 >> 12;
    int zlo = zq*4;

    float ax[4], ay[4], az[4], mm[4];
    #pragma unroll
    for (int h = 0; h < 4; ++h) { ax[h]=0.f; ay[h]=0.f; az[h]=0.f; mm[h]=0.f; }

    int bk0 = max(zlo-2, 0), bk1 = min(zlo+3, NG-3);

    // prefetch all 9 column ranges (statically indexed -> stays in registers)
    int sArr[3][3], eArr[3][3];
    #pragma unroll
    for (int di = 0; di < 3; ++di) {
        int bi = gi - 2 + di;
        bool vi = (bi >= 0) && (bi <= NG-3);
        #pragma unroll
        for (int dj = 0; dj < 3; ++dj) {
            int bj = gj - 2 + dj;
            bool vj = vi && (bj >= 0) && (bj <= NG-3);
            int col = ((vj ? bi : 0)*NG + (vj ? bj : 0))*NG;
            sArr[di][dj] = vj ? offset[col + bk0]     : 0;
            eArr[di][dj] = vj ? offset[col + bk1 + 1] : 0;
        }
    }

    bool any = false;
    #pragma unroll
    for (int di = 0; di < 3; ++di)
        #pragma unroll
        for (int dj = 0; dj < 3; ++dj)
            if (sArr[di][dj] < eArr[di][dj]) any = true;

    float gif = (float)gi, gjf = (float)gj, z0f = (float)zlo;

    // per-particle body (weight pre-masked by msk)
    auto body = [&](const float4& r0, const float4& r1, const float4& r2,
                    const float4& r3, float msk) {
        // symmetric quadratic B-spline N(u), u = cell - A (fp-exact vs ref)
        float ux = gif - r0.x;
        float aux = fabsf(ux);
        float tx = 1.5f - aux;
        float nx = (aux < 0.5f) ? (0.75f - ux*ux) : (0.5f*tx*tx);
        float uy = gjf - r0.y;
        float auy = fabsf(uy);
        float ty = 1.5f - auy;
        float ny = (auy < 0.5f) ? (0.75f - uy*uy) : (0.5f*ty*ty);
        float wgt = nx*ny*msk;             // reference: x,y weights only

        float uz0 = z0f - r0.z;
        float dpx = ux*c_DX, dpy = uy*c_DX, dpz0 = uz0*c_DX;
        float cx = r3.y + r1.x*dpx + r1.y*dpy + r1.z*dpz0;
        float cy = r3.z + r1.w*dpx + r2.x*dpy + r2.y*dpz0;
        float cz = r3.w + r2.z*dpx + r2.w*dpy + r3.x*dpz0;
        float ix = r1.z*c_DX, iy = r2.y*c_DX, iz = r3.x*c_DX;

        #pragma unroll
        for (int h = 0; h < 4; ++h) {
            float uz = uz0 + (float)h;
            // membership mask: uz in (-1.5, 1.5]
            float w = (uz > -1.5f && uz <= 1.5f) ? wgt : 0.f;
            ax[h] += w*cx; ay[h] += w*cy; az[h] += w*cz; mm[h] += w*P_MASS;
            cx += ix; cy += iy; cz += iz;
        }
    };

    #pragma unroll
    for (int di = 0; di < 3; ++di) {
        #pragma unroll
        for (int dj = 0; dj < 3; ++dj) {
            int s = sArr[di][dj], e = eArr[di][dj];
            for (int p = s; p < e; p += 2) {
                const float4* rpA = (const float4*)&rec[p];
                float4 a0 = rpA[0], a1 = rpA[1], a2 = rpA[2], a3 = rpA[3];
                int pB = (p+1 < e) ? p+1 : p;
                float mB = (p+1 < e) ? 1.f : 0.f;
                const float4* rpB = (const float4*)&rec[pB];
                float4 b0 = rpB[0], b1 = rpB[1], b2 = rpB[2], b3 = rpB[3];
                body(a0, a1, a2, a3, 1.f);
                body(b0, b1, b2, b3, mB);
            }
        }
    }

    // quads with zero visits are never read by g2p (any cell g2p reads has a
    // member particle, and member particles lie in this quad's bucket window)
    if (!any) return;

    float gx = DT*gravity[0]*30.0f, gy = DT*gravity[1]*30.0f, gz = DT*gravity[2]*30.0f;
    float apx = attr_p[0], apy = attr_p[1], apz = attr_p[2];
    float as  = attr_s[0] * DT * 100.0f;

    int gidx = (gi*NG + gj)*NG + zlo;
    #pragma unroll
    for (int h = 0; h < 4; ++h) {
        float m = mm[h];
        int gk = zlo + h;
        float gvx = 0.f, gvy = 0.f, gvz = 0.f;
        if (m > 0.f) {
            float inv = 1.0f/m;
            gvx = ax[h]*inv + gx; gvy = ay[h]*inv + gy; gvz = az[h]*inv + gz;
            float dx_ = apx - c_DX*(float)gi;
            float dy_ = apy - c_DX*(float)gj;
            float dz_ = apz - c_DX*(float)gk;
            float nrm = sqrtf(dx_*dx_ + dy_*dy_ + dz_*dz_);
            float sc = as / (0.01f + nrm);
            gvx += dx_*sc; gvy += dy_*sc; gvz += dz_*sc;
            if (gi < 3      && gvx < 0.f) gvx = 0.f;
            if (gi > NG-3   && gvx > 0.f) gvx = 0.f;
            if (gj < 3      && gvy < 0.f) gvy = 0.f;
            if (gj > NG-3   && gvy > 0.f) gvy = 0.f;
            // z unconstrained (matches reference)
        }
        grid[gidx + h] = make_float4(gvx, gvy, gvz, m);
    }
}

// ---------------- G2P (cell-sorted order, coalesced record reads) ----------------
__global__ void __launch_bounds__(256)
g2p_kernel(const PRec* __restrict__ rec, const float4* __restrict__ grid,
           float* __restrict__ out, int N) {
    int gid = blockIdx.x * 256 + threadIdx.x;
    if (gid >= N) return;

    float4 r0 = rec[gid].r0;
    float A0 = r0.x, A1 = r0.y, A2 = r0.z;
    int n = __float_as_int(r0.w);

    int bi, bj, bk; float fx0, fx1, fx2;
    base_from_A(A0, A1, A2, bi, bj, bk, fx0, fx1, fx2);

    float wx[3], wy[3];
    wx[0] = 0.5f*(1.5f-fx0)*(1.5f-fx0); wx[1] = 0.75f-(fx0-1.f)*(fx0-1.f); wx[2] = 0.5f*(fx0-0.5f)*(fx0-0.5f);
    wy[0] = 0.5f*(1.5f-fx1)*(1.5f-fx1); wy[1] = 0.75f-(fx1-1.f)*(fx1-1.f); wy[2] = 0.5f*(fx1-0.5f)*(fx1-0.5f);

    float nvx = 0.f, nvy = 0.f, nvz = 0.f;
    float nC[9];
    #pragma unroll
    for (int i = 0; i < 9; ++i) nC[i] = 0.f;

    #pragma unroll
    for (int i = 0; i < 3; ++i) {
        float dpx = (float)i - fx0;
        #pragma unroll
        for (int j = 0; j < 3; ++j) {
            float wgt = wx[i]*wy[j];
            float dpy = (float)j - fx1;
            int cell0 = ((bi+i)*NG + (bj+j))*NG + bk;
            #pragma unroll
            for (int k = 0; k < 3; ++k) {
                float dpz = (float)k - fx2;
                float4 gv = grid[cell0 + k];
                float wgx = wgt*gv.x, wgy = wgt*gv.y, wgz = wgt*gv.z;
                nvx += wgx; nvy += wgy; nvz += wgz;
                nC[0] += wgx*dpx; nC[1] += wgx*dpy; nC[2] += wgx*dpz;
                nC[3] += wgy*dpx; nC[4] += wgy*dpy; nC[5] += wgy*dpz;
                nC[6] += wgz*dpx; nC[7] += wgz*dpy; nC[8] += wgz*dpz;
            }
        }
    }

    float* po = out + (size_t)n*25;
    float px = A0*c_DX, py = A1*c_DX, pz = A2*c_DX;   // exact reconstruction
    po[0] = px + DT*nvx;
    po[1] = py + DT*nvy;
    po[2] = pz + DT*nvz;
    po[3] = nvx; po[4] = nvy; po[5] = nvz;
    float s4 = 4.0f*c_INV_DX;
    #pragma unroll
    for (int i = 0; i < 9; ++i) po[16+i] = s4*nC[i];
}

extern "C" void kernel_launch(void* const* d_in, const int* in_sizes, int n_in,
                              void* d_out, int out_size, void* d_ws, size_t ws_size,
                              hipStream_t stream) {
    const float* x        = (const float*)d_in[0];
    const float* v        = (const float*)d_in[1];
    const float* C        = (const float*)d_in[2];
    const float* F        = (const float*)d_in[3];
    const float* Jp       = (const float*)d_in[4];
    const float* gravity  = (const float*)d_in[5];
    const float* attr_s   = (const float*)d_in[6];
    const float* attr_p   = (const float*)d_in[7];
    const int*   material = (const int*)d_in[8];
    float* out = (float*)d_out;
    int N = in_sizes[0] / 3;

    // workspace: [count G3] (zeroed) [offset G3+1][partial][rank N][grid][rec]
    char* ws = (char*)d_ws;
    size_t o = 0;
    int* cell_count = (int*)(ws + o);      o += (size_t)G3*sizeof(int);
    size_t zero_bytes = o;
    int* offset     = (int*)(ws + o);      o += ((size_t)G3+1)*sizeof(int);
    int* partial    = (int*)(ws + o);      o += (size_t)NSCAN_BLOCKS*sizeof(int);
    int* rank       = (int*)(ws + o);      o += (size_t)N*sizeof(int);
    o = (o + 127) & ~(size_t)127;
    float4* grid    = (float4*)(ws + o);   o += (size_t)G3*sizeof(float4);
    PRec* rec       = (PRec*)(ws + o);     o += (size_t)N*sizeof(PRec);

    hipMemsetAsync(d_ws, 0, zero_bytes, stream);

    int pblocks = (N + 255) / 256;
    count_kernel<<<pblocks, 256, 0, stream>>>(x, cell_count, rank, N);
    scan_partial_kernel<<<NSCAN_BLOCKS, 256, 0, stream>>>(cell_count, partial);
    scan_partials_kernel<<<1, 256, 0, stream>>>(partial);
    scan_final_kernel<<<NSCAN_BLOCKS, 256, 0, stream>>>(cell_count, partial, offset);
    pre_kernel<<<pblocks, 256, 0, stream>>>(x, v, C, F, Jp, material,
                                            offset, rank, rec, out, N);
    grid_gather_kernel<<<G3/1024, 256, 0, stream>>>(rec, offset, grid,
                                                    gravity, attr_s, attr_p);
    g2p_kernel<<<pblocks, 256, 0, stream>>>(rec, grid, out, N);
}

// Round 3
// 276.939 us; speedup vs baseline: 1.9968x; 1.0191x over previous
//
#include <hip/hip_runtime.h>

#define NG 128
#define G3 (NG*NG*NG)
#define NSCAN_BLOCKS (G3/256)   // 8192

__device__ __constant__ const float c_DX      = 1.0f/128.0f;
__device__ __constant__ const float c_INV_DX  = 128.0f;

#define DT      1e-4f
#define P_VOL   ((1.0f/256.0f)*(1.0f/256.0f))
#define P_MASS  P_VOL
#define MU0     (5000.0f/(2.0f*1.2f))
#define LAM0    (5000.0f*0.2f/(1.2f*0.6f))

// 64-byte packed particle record, stored in cell-bucket order
// r0 = {A0, A1, A2, particle_id}   A = x*INV_DX (absolute grid coord; exact)
// r1 = {aff0..3}, r2 = {aff4..7}, r3 = {aff8, mv0, mv1, mv2}
struct __align__(16) PRec {
    float4 r0, r1, r2, r3;
};

// ---------------- 3x3 SVD via Jacobi on A^T A ----------------
__device__ inline void jacobi_rot(float S[3][3], float V[3][3], int p, int q) {
    float apq = S[p][q];
    if (fabsf(apq) < 1e-24f) return;
    float tau = (S[q][q] - S[p][p]) / (2.0f * apq);
    float t = copysignf(1.0f, tau) / (fabsf(tau) + sqrtf(1.0f + tau*tau));
    float c = rsqrtf(1.0f + t*t);
    float sn = t * c;
    #pragma unroll
    for (int k = 0; k < 3; ++k) {
        float Spk = S[p][k], Sqk = S[q][k];
        S[p][k] = c*Spk - sn*Sqk;
        S[q][k] = sn*Spk + c*Sqk;
    }
    #pragma unroll
    for (int k = 0; k < 3; ++k) {
        float Skp = S[k][p], Skq = S[k][q];
        S[k][p] = c*Skp - sn*Skq;
        S[k][q] = sn*Skp + c*Skq;
    }
    #pragma unroll
    for (int k = 0; k < 3; ++k) {
        float Vkp = V[k][p], Vkq = V[k][q];
        V[k][p] = c*Vkp - sn*Vkq;
        V[k][q] = sn*Vkp + c*Vkq;
    }
}

__device__ inline void svd3(const float A[9], float U[9], float sv[3], float V[9]) {
    float S[3][3];
    #pragma unroll
    for (int i = 0; i < 3; ++i)
        #pragma unroll
        for (int j = 0; j < 3; ++j) {
            float acc = 0.f;
            #pragma unroll
            for (int k = 0; k < 3; ++k) acc += A[k*3+i]*A[k*3+j];
            S[i][j] = acc;
        }
    float Vm[3][3] = {{1.f,0.f,0.f},{0.f,1.f,0.f},{0.f,0.f,1.f}};
    #pragma unroll
    for (int sweep = 0; sweep < 4; ++sweep) {
        jacobi_rot(S, Vm, 0, 1);
        jacobi_rot(S, Vm, 0, 2);
        jacobi_rot(S, Vm, 1, 2);
    }
    float lam[3] = {S[0][0], S[1][1], S[2][2]};
    int i0 = 0, i1 = 1, i2 = 2, t;
    if (lam[i0] < lam[i1]) { t = i0; i0 = i1; i1 = t; }
    if (lam[i0] < lam[i2]) { t = i0; i0 = i2; i2 = t; }
    if (lam[i1] < lam[i2]) { t = i1; i1 = i2; i2 = t; }
    int ord[3] = {i0, i1, i2};
    #pragma unroll
    for (int c = 0; c < 3; ++c) {
        int s_ = ord[c];
        float l = fmaxf(lam[s_], 0.f);
        float sval = sqrtf(l);
        sv[c] = sval;
        float v0 = Vm[0][s_], v1 = Vm[1][s_], v2 = Vm[2][s_];
        V[0*3+c] = v0; V[1*3+c] = v1; V[2*3+c] = v2;
        float inv = (sval > 1e-12f) ? 1.0f/sval : 0.f;
        U[0*3+c] = (A[0]*v0 + A[1]*v1 + A[2]*v2)*inv;
        U[1*3+c] = (A[3]*v0 + A[4]*v1 + A[5]*v2)*inv;
        U[2*3+c] = (A[6]*v0 + A[7]*v1 + A[8]*v2)*inv;
    }
}

// ---------------- binning helpers ----------------
// from absolute grid coord A: base cell + frac (all fp-exact)
__device__ inline void base_from_A(float A0, float A1, float A2,
                                   int& bi, int& bj, int& bk,
                                   float& fx0, float& fx1, float& fx2) {
    float bxf = floorf(A0 - 0.5f);
    float byf = floorf(A1 - 0.5f);
    float bzf = floorf(A2 - 0.5f);
    bi = (int)bxf; bj = (int)byf; bk = (int)bzf;
    bi = min(max(bi, 0), NG-3); bj = min(max(bj, 0), NG-3); bk = min(max(bk, 0), NG-3);
    fx0 = A0 - bxf;
    fx1 = A1 - byf;
    fx2 = A2 - bzf;
}

// count + per-particle rank within its cell (atomicAdd's return value)
__global__ void __launch_bounds__(256)
count_kernel(const float* __restrict__ x, int* __restrict__ cell_count,
             int* __restrict__ rank, int N) {
    int n = blockIdx.x*256 + threadIdx.x;
    if (n >= N) return;
    int bi, bj, bk; float f0, f1, f2;
    base_from_A(x[3*n+0]*c_INV_DX, x[3*n+1]*c_INV_DX, x[3*n+2]*c_INV_DX,
                bi, bj, bk, f0, f1, f2);
    rank[n] = atomicAdd(&cell_count[(bi*NG + bj)*NG + bk], 1);
}

// ---- scan stage A: per-block (256 elems) reduction -> partial[block] ----
__global__ void __launch_bounds__(256)
scan_partial_kernel(const int* __restrict__ count, int* __restrict__ partial) {
    __shared__ int red[256];
    int t = threadIdx.x;
    red[t] = count[blockIdx.x*256 + t];
    __syncthreads();
    for (int off = 128; off > 0; off >>= 1) {
        if (t < off) red[t] += red[t+off];
        __syncthreads();
    }
    if (t == 0) partial[blockIdx.x] = red[0];
}

// ---- scan stage B: exclusive scan of 8192 partials, 1 block, 256x32 ----
__global__ void __launch_bounds__(256)
scan_partials_kernel(int* __restrict__ partial) {
    __shared__ int part[256];
    int t = threadIdx.x;
    int base = t*32;
    int local[32];
    int s = 0;
    #pragma unroll
    for (int i = 0; i < 32; ++i) { local[i] = s; s += partial[base+i]; }
    part[t] = s;
    __syncthreads();
    for (int off = 1; off < 256; off <<= 1) {
        int v = (t >= off) ? part[t-off] : 0;
        __syncthreads();
        part[t] += v;
        __syncthreads();
    }
    int prev = (t == 0) ? 0 : part[t-1];
    #pragma unroll
    for (int i = 0; i < 32; ++i) partial[base+i] = prev + local[i];
}

// ---- scan stage C: block-level exclusive scan + partial base -> offset ----
__global__ void __launch_bounds__(256)
scan_final_kernel(const int* __restrict__ count, const int* __restrict__ partial,
                  int* __restrict__ offset) {
    __shared__ int part[256];
    int t = threadIdx.x;
    int i = blockIdx.x*256 + t;
    int c = count[i];
    part[t] = c;
    __syncthreads();
    for (int off = 1; off < 256; off <<= 1) {
        int v = (t >= off) ? part[t-off] : 0;
        __syncthreads();
        part[t] += v;
        __syncthreads();
    }
    int base = partial[blockIdx.x];
    offset[i] = base + part[t] - c;
    if (i == G3-1) offset[G3] = base + part[t];
}

// ---------------- pre-pass: all per-particle math, coalesced reads ----------------
__global__ void __launch_bounds__(256)
pre_kernel(const float* __restrict__ x, const float* __restrict__ v,
           const float* __restrict__ Cin, const float* __restrict__ Fin,
           const float* __restrict__ Jp_in, const int* __restrict__ material,
           const int* __restrict__ offset, const int* __restrict__ rank,
           PRec* __restrict__ rec, float* __restrict__ out, int N) {
    int n = blockIdx.x*256 + threadIdx.x;
    if (n >= N) return;

    float A0 = x[3*n+0]*c_INV_DX, A1 = x[3*n+1]*c_INV_DX, A2 = x[3*n+2]*c_INV_DX;
    int bi, bj, bk; float f0, f1, f2;
    base_from_A(A0, A1, A2, bi, bj, bk, f0, f1, f2);

    float Cm[9], Fm[9];
    #pragma unroll
    for (int i = 0; i < 9; ++i) { Cm[i] = Cin[9*n+i]; Fm[i] = Fin[9*n+i]; }

    // Fn = (I + DT*C) @ F
    float Fn[9];
    #pragma unroll
    for (int i = 0; i < 3; ++i)
        #pragma unroll
        for (int k = 0; k < 3; ++k) {
            float acc = Fm[i*3+k];
            #pragma unroll
            for (int j = 0; j < 3; ++j) acc += DT * Cm[i*3+j] * Fm[j*3+k];
            Fn[i*3+k] = acc;
        }

    float Jp = Jp_in[n];
    int mat = material[n];
    float h = expf(10.0f*(1.0f - Jp));
    h = fminf(fmaxf(h, 0.1f), 5.0f);
    if (mat == 1) h = 0.3f;
    float mu = (mat == 0) ? 0.0f : MU0*h;
    float la = LAM0*h;

    float U[9], V[9], sv[3];
    svd3(Fn, U, sv, V);

    float J = 1.0f;
    float sig[3];
    #pragma unroll
    for (int d = 0; d < 2; ++d) {
        float s = sv[d];
        float ns = (mat == 2) ? fminf(fmaxf(s, 1.0f-0.025f), 1.0f+0.0045f) : s;
        Jp = Jp * s / ns;
        sig[d] = ns;
        J *= ns;
    }
    sig[2] = sv[2];

    if (mat == 0) {
        float sj = sqrtf(J);
        Fn[0]=sj; Fn[1]=0; Fn[2]=0; Fn[3]=0; Fn[4]=sj; Fn[5]=0; Fn[6]=0; Fn[7]=0; Fn[8]=sj;
    } else if (mat == 2) {
        #pragma unroll
        for (int i = 0; i < 3; ++i)
            #pragma unroll
            for (int k = 0; k < 3; ++k) {
                float acc = 0.f;
                #pragma unroll
                for (int j = 0; j < 3; ++j) acc += U[i*3+j]*sig[j]*V[k*3+j];
                Fn[i*3+k] = acc;
            }
    }

    float R[9];
    #pragma unroll
    for (int i = 0; i < 3; ++i)
        #pragma unroll
        for (int k = 0; k < 3; ++k) {
            float acc = 0.f;
            #pragma unroll
            for (int j = 0; j < 3; ++j) acc += U[i*3+j]*V[k*3+j];
            R[i*3+k] = acc;
        }

    float press = la * J * (J - 1.0f);
    float scale = -DT * P_VOL * 4.0f * c_INV_DX * c_INV_DX;
    float aff[9];
    #pragma unroll
    for (int i = 0; i < 3; ++i)
        #pragma unroll
        for (int k = 0; k < 3; ++k) {
            float acc = 0.f;
            #pragma unroll
            for (int j = 0; j < 3; ++j) acc += (Fn[i*3+j]-R[i*3+j])*Fn[k*3+j];
            acc = 2.0f*mu*acc;
            if (i == k) acc += press;
            aff[i*3+k] = scale*acc + P_MASS*Cm[i*3+k];
        }

    float* po = out + (size_t)n*25;
    po[6] = Jp;
    #pragma unroll
    for (int i = 0; i < 9; ++i) po[7+i] = Fn[i];

    // cell-bucket slot (rank captured by count_kernel's atomicAdd)
    int cell = (bi*NG + bj)*NG + bk;
    int pos = offset[cell] + rank[n];

    float4* rp = (float4*)&rec[pos];
    rp[0] = make_float4(A0, A1, A2, __int_as_float(n));
    rp[1] = make_float4(aff[0], aff[1], aff[2], aff[3]);
    rp[2] = make_float4(aff[4], aff[5], aff[6], aff[7]);
    rp[3] = make_float4(aff[8], P_MASS*v[3*n+0], P_MASS*v[3*n+1], P_MASS*v[3*n+2]);
}

// ------- fused P2G-gather + grid update: one thread per 4 z-cells, NO atomics ----
// v3: (a) all 9 column ranges prefetched up-front (18 independent loads in
//     flight; round-2 data: cuts FETCH_SIZE 60MB -> 22MB);
// (b) lean 1-body inner loop (round-2's 2-wide unroll regressed: +16 VGPR,
//     dual-body issue waste);
// (c) 128-thread blocks (4096 blocks): no LDS/barriers in this kernel, so
//     smaller blocks double the scheduler's re-balancing granules and cut
//     the heavy-block tail (occupancy was draining to 30%).
__global__ void __launch_bounds__(128)
grid_gather_kernel(const PRec* __restrict__ rec, const int* __restrict__ offset,
                   float4* __restrict__ grid, const float* __restrict__ gravity,
                   const float* __restrict__ attr_s, const float* __restrict__ attr_p) {
    int g4 = blockIdx.x*128 + threadIdx.x;   // quad index (G3/4 total)
    int zq = g4 & 31;
    int gj = (g4 >> 5) & (NG-1);
    int gi = g4 >> 12;
    int zlo = zq*4;

    float ax[4], ay[4], az[4], mm[4];
    #pragma unroll
    for (int h = 0; h < 4; ++h) { ax[h]=0.f; ay[h]=0.f; az[h]=0.f; mm[h]=0.f; }

    int bk0 = max(zlo-2, 0), bk1 = min(zlo+3, NG-3);

    // prefetch all 9 column ranges (statically indexed -> stays in registers)
    int sArr[3][3], eArr[3][3];
    #pragma unroll
    for (int di = 0; di < 3; ++di) {
        int bi = gi - 2 + di;
        bool vi = (bi >= 0) && (bi <= NG-3);
        #pragma unroll
        for (int dj = 0; dj < 3; ++dj) {
            int bj = gj - 2 + dj;
            bool vj = vi && (bj >= 0) && (bj <= NG-3);
            int col = ((vj ? bi : 0)*NG + (vj ? bj : 0))*NG;
            sArr[di][dj] = vj ? offset[col + bk0]     : 0;
            eArr[di][dj] = vj ? offset[col + bk1 + 1] : 0;
        }
    }

    bool any = false;
    #pragma unroll
    for (int di = 0; di < 3; ++di)
        #pragma unroll
        for (int dj = 0; dj < 3; ++dj)
            if (sArr[di][dj] < eArr[di][dj]) any = true;

    float gif = (float)gi, gjf = (float)gj, z0f = (float)zlo;

    #pragma unroll
    for (int di = 0; di < 3; ++di) {
        #pragma unroll
        for (int dj = 0; dj < 3; ++dj) {
            int s = sArr[di][dj], e = eArr[di][dj];
            for (int p = s; p < e; ++p) {
                const float4* rp = (const float4*)&rec[p];
                float4 r0 = rp[0];
                float4 r1 = rp[1];
                float4 r2 = rp[2];
                float4 r3 = rp[3];

                // symmetric quadratic B-spline N(u), u = cell - A (fp-exact vs ref)
                float ux = gif - r0.x;
                float aux = fabsf(ux);
                float tx = 1.5f - aux;
                float nx = (aux < 0.5f) ? (0.75f - ux*ux) : (0.5f*tx*tx);
                float uy = gjf - r0.y;
                float auy = fabsf(uy);
                float ty = 1.5f - auy;
                float ny = (auy < 0.5f) ? (0.75f - uy*uy) : (0.5f*ty*ty);
                float wgt = nx*ny;                 // reference: x,y weights only

                float uz0 = z0f - r0.z;
                float dpx = ux*c_DX, dpy = uy*c_DX, dpz0 = uz0*c_DX;
                float cx = r3.y + r1.x*dpx + r1.y*dpy + r1.z*dpz0;
                float cy = r3.z + r1.w*dpx + r2.x*dpy + r2.y*dpz0;
                float cz = r3.w + r2.z*dpx + r2.w*dpy + r3.x*dpz0;
                float ix = r1.z*c_DX, iy = r2.y*c_DX, iz = r3.x*c_DX;

                #pragma unroll
                for (int h = 0; h < 4; ++h) {
                    float uz = uz0 + (float)h;
                    // membership mask: uz in (-1.5, 1.5]
                    float w = (uz > -1.5f && uz <= 1.5f) ? wgt : 0.f;
                    ax[h] += w*cx; ay[h] += w*cy; az[h] += w*cz; mm[h] += w*P_MASS;
                    cx += ix; cy += iy; cz += iz;
                }
            }
        }
    }

    // quads with zero visits are never read by g2p (any cell g2p reads has a
    // member particle, and member particles lie in this quad's bucket window)
    if (!any) return;

    float gx = DT*gravity[0]*30.0f, gy = DT*gravity[1]*30.0f, gz = DT*gravity[2]*30.0f;
    float apx = attr_p[0], apy = attr_p[1], apz = attr_p[2];
    float as  = attr_s[0] * DT * 100.0f;

    int gidx = (gi*NG + gj)*NG + zlo;
    #pragma unroll
    for (int h = 0; h < 4; ++h) {
        float m = mm[h];
        int gk = zlo + h;
        float gvx = 0.f, gvy = 0.f, gvz = 0.f;
        if (m > 0.f) {
            float inv = 1.0f/m;
            gvx = ax[h]*inv + gx; gvy = ay[h]*inv + gy; gvz = az[h]*inv + gz;
            float dx_ = apx - c_DX*(float)gi;
            float dy_ = apy - c_DX*(float)gj;
            float dz_ = apz - c_DX*(float)gk;
            float nrm = sqrtf(dx_*dx_ + dy_*dy_ + dz_*dz_);
            float sc = as / (0.01f + nrm);
            gvx += dx_*sc; gvy += dy_*sc; gvz += dz_*sc;
            if (gi < 3      && gvx < 0.f) gvx = 0.f;
            if (gi > NG-3   && gvx > 0.f) gvx = 0.f;
            if (gj < 3      && gvy < 0.f) gvy = 0.f;
            if (gj > NG-3   && gvy > 0.f) gvy = 0.f;
            // z unconstrained (matches reference)
        }
        grid[gidx + h] = make_float4(gvx, gvy, gvz, m);
    }
}

// ---------------- G2P (cell-sorted order, coalesced record reads) ----------------
__global__ void __launch_bounds__(256)
g2p_kernel(const PRec* __restrict__ rec, const float4* __restrict__ grid,
           float* __restrict__ out, int N) {
    int gid = blockIdx.x * 256 + threadIdx.x;
    if (gid >= N) return;

    float4 r0 = rec[gid].r0;
    float A0 = r0.x, A1 = r0.y, A2 = r0.z;
    int n = __float_as_int(r0.w);

    int bi, bj, bk; float fx0, fx1, fx2;
    base_from_A(A0, A1, A2, bi, bj, bk, fx0, fx1, fx2);

    float wx[3], wy[3];
    wx[0] = 0.5f*(1.5f-fx0)*(1.5f-fx0); wx[1] = 0.75f-(fx0-1.f)*(fx0-1.f); wx[2] = 0.5f*(fx0-0.5f)*(fx0-0.5f);
    wy[0] = 0.5f*(1.5f-fx1)*(1.5f-fx1); wy[1] = 0.75f-(fx1-1.f)*(fx1-1.f); wy[2] = 0.5f*(fx1-0.5f)*(fx1-0.5f);

    float nvx = 0.f, nvy = 0.f, nvz = 0.f;
    float nC[9];
    #pragma unroll
    for (int i = 0; i < 9; ++i) nC[i] = 0.f;

    #pragma unroll
    for (int i = 0; i < 3; ++i) {
        float dpx = (float)i - fx0;
        #pragma unroll
        for (int j = 0; j < 3; ++j) {
            float wgt = wx[i]*wy[j];
            float dpy = (float)j - fx1;
            int cell0 = ((bi+i)*NG + (bj+j))*NG + bk;
            #pragma unroll
            for (int k = 0; k < 3; ++k) {
                float dpz = (float)k - fx2;
                float4 gv = grid[cell0 + k];
                float wgx = wgt*gv.x, wgy = wgt*gv.y, wgz = wgt*gv.z;
                nvx += wgx; nvy += wgy; nvz += wgz;
                nC[0] += wgx*dpx; nC[1] += wgx*dpy; nC[2] += wgx*dpz;
                nC[3] += wgy*dpx; nC[4] += wgy*dpy; nC[5] += wgy*dpz;
                nC[6] += wgz*dpx; nC[7] += wgz*dpy; nC[8] += wgz*dpz;
            }
        }
    }

    float* po = out + (size_t)n*25;
    float px = A0*c_DX, py = A1*c_DX, pz = A2*c_DX;   // exact reconstruction
    po[0] = px + DT*nvx;
    po[1] = py + DT*nvy;
    po[2] = pz + DT*nvz;
    po[3] = nvx; po[4] = nvy; po[5] = nvz;
    float s4 = 4.0f*c_INV_DX;
    #pragma unroll
    for (int i = 0; i < 9; ++i) po[16+i] = s4*nC[i];
}

extern "C" void kernel_launch(void* const* d_in, const int* in_sizes, int n_in,
                              void* d_out, int out_size, void* d_ws, size_t ws_size,
                              hipStream_t stream) {
    const float* x        = (const float*)d_in[0];
    const float* v        = (const float*)d_in[1];
    const float* C        = (const float*)d_in[2];
    const float* F        = (const float*)d_in[3];
    const float* Jp       = (const float*)d_in[4];
    const float* gravity  = (const float*)d_in[5];
    const float* attr_s   = (const float*)d_in[6];
    const float* attr_p   = (const float*)d_in[7];
    const int*   material = (const int*)d_in[8];
    float* out = (float*)d_out;
    int N = in_sizes[0] / 3;

    // workspace: [count G3] (zeroed) [offset G3+1][partial][rank N][grid][rec]
    char* ws = (char*)d_ws;
    size_t o = 0;
    int* cell_count = (int*)(ws + o);      o += (size_t)G3*sizeof(int);
    size_t zero_bytes = o;
    int* offset     = (int*)(ws + o);      o += ((size_t)G3+1)*sizeof(int);
    int* partial    = (int*)(ws + o);      o += (size_t)NSCAN_BLOCKS*sizeof(int);
    int* rank       = (int*)(ws + o);      o += (size_t)N*sizeof(int);
    o = (o + 127) & ~(size_t)127;
    float4* grid    = (float4*)(ws + o);   o += (size_t)G3*sizeof(float4);
    PRec* rec       = (PRec*)(ws + o);     o += (size_t)N*sizeof(PRec);

    hipMemsetAsync(d_ws, 0, zero_bytes, stream);

    int pblocks = (N + 255) / 256;
    count_kernel<<<pblocks, 256, 0, stream>>>(x, cell_count, rank, N);
    scan_partial_kernel<<<NSCAN_BLOCKS, 256, 0, stream>>>(cell_count, partial);
    scan_partials_kernel<<<1, 256, 0, stream>>>(partial);
    scan_final_kernel<<<NSCAN_BLOCKS, 256, 0, stream>>>(cell_count, partial, offset);
    pre_kernel<<<pblocks, 256, 0, stream>>>(x, v, C, F, Jp, material,
                                            offset, rank, rec, out, N);
    grid_gather_kernel<<<G3/512, 128, 0, stream>>>(rec, offset, grid,
                                                   gravity, attr_s, attr_p);
    g2p_kernel<<<pblocks, 256, 0, stream>>>(rec, grid, out, N);
}

// Round 4
// 260.711 us; speedup vs baseline: 2.1212x; 1.0622x over previous
//
#include <hip/hip_runtime.h>

#define NG 128
#define G3 (NG*NG*NG)
#define NSCAN_BLOCKS (G3/256)   // 8192

__device__ __constant__ const float c_DX      = 1.0f/128.0f;
__device__ __constant__ const float c_INV_DX  = 128.0f;

#define DT      1e-4f
#define P_VOL   ((1.0f/256.0f)*(1.0f/256.0f))
#define P_MASS  P_VOL
#define MU0     (5000.0f/(2.0f*1.2f))
#define LAM0    (5000.0f*0.2f/(1.2f*0.6f))

// 64-byte packed particle record, stored in cell-bucket order
// r0 = {A0, A1, A2, particle_id}   A = x*INV_DX (absolute grid coord; exact)
// r1 = {aff0..3}, r2 = {aff4..7}, r3 = {aff8, mv0, mv1, mv2}
struct __align__(16) PRec {
    float4 r0, r1, r2, r3;
};

// ---------------- 3x3 SVD via Jacobi on A^T A ----------------
__device__ inline void jacobi_rot(float S[3][3], float V[3][3], int p, int q) {
    float apq = S[p][q];
    if (fabsf(apq) < 1e-24f) return;
    float tau = (S[q][q] - S[p][p]) / (2.0f * apq);
    float t = copysignf(1.0f, tau) / (fabsf(tau) + sqrtf(1.0f + tau*tau));
    float c = rsqrtf(1.0f + t*t);
    float sn = t * c;
    #pragma unroll
    for (int k = 0; k < 3; ++k) {
        float Spk = S[p][k], Sqk = S[q][k];
        S[p][k] = c*Spk - sn*Sqk;
        S[q][k] = sn*Spk + c*Sqk;
    }
    #pragma unroll
    for (int k = 0; k < 3; ++k) {
        float Skp = S[k][p], Skq = S[k][q];
        S[k][p] = c*Skp - sn*Skq;
        S[k][q] = sn*Skp + c*Skq;
    }
    #pragma unroll
    for (int k = 0; k < 3; ++k) {
        float Vkp = V[k][p], Vkq = V[k][q];
        V[k][p] = c*Vkp - sn*Vkq;
        V[k][q] = sn*Vkp + c*Vkq;
    }
}

__device__ inline void svd3(const float A[9], float U[9], float sv[3], float V[9]) {
    float S[3][3];
    #pragma unroll
    for (int i = 0; i < 3; ++i)
        #pragma unroll
        for (int j = 0; j < 3; ++j) {
            float acc = 0.f;
            #pragma unroll
            for (int k = 0; k < 3; ++k) acc += A[k*3+i]*A[k*3+j];
            S[i][j] = acc;
        }
    float Vm[3][3] = {{1.f,0.f,0.f},{0.f,1.f,0.f},{0.f,0.f,1.f}};
    #pragma unroll
    for (int sweep = 0; sweep < 4; ++sweep) {
        jacobi_rot(S, Vm, 0, 1);
        jacobi_rot(S, Vm, 0, 2);
        jacobi_rot(S, Vm, 1, 2);
    }
    float lam[3] = {S[0][0], S[1][1], S[2][2]};
    int i0 = 0, i1 = 1, i2 = 2, t;
    if (lam[i0] < lam[i1]) { t = i0; i0 = i1; i1 = t; }
    if (lam[i0] < lam[i2]) { t = i0; i0 = i2; i2 = t; }
    if (lam[i1] < lam[i2]) { t = i1; i1 = i2; i2 = t; }
    int ord[3] = {i0, i1, i2};
    #pragma unroll
    for (int c = 0; c < 3; ++c) {
        int s_ = ord[c];
        float l = fmaxf(lam[s_], 0.f);
        float sval = sqrtf(l);
        sv[c] = sval;
        float v0 = Vm[0][s_], v1 = Vm[1][s_], v2 = Vm[2][s_];
        V[0*3+c] = v0; V[1*3+c] = v1; V[2*3+c] = v2;
        float inv = (sval > 1e-12f) ? 1.0f/sval : 0.f;
        U[0*3+c] = (A[0]*v0 + A[1]*v1 + A[2]*v2)*inv;
        U[1*3+c] = (A[3]*v0 + A[4]*v1 + A[5]*v2)*inv;
        U[2*3+c] = (A[6]*v0 + A[7]*v1 + A[8]*v2)*inv;
    }
}

// ---------------- binning helpers ----------------
// from absolute grid coord A: base cell + frac (all fp-exact)
__device__ inline void base_from_A(float A0, float A1, float A2,
                                   int& bi, int& bj, int& bk,
                                   float& fx0, float& fx1, float& fx2) {
    float bxf = floorf(A0 - 0.5f);
    float byf = floorf(A1 - 0.5f);
    float bzf = floorf(A2 - 0.5f);
    bi = (int)bxf; bj = (int)byf; bk = (int)bzf;
    bi = min(max(bi, 0), NG-3); bj = min(max(bj, 0), NG-3); bk = min(max(bk, 0), NG-3);
    fx0 = A0 - bxf;
    fx1 = A1 - byf;
    fx2 = A2 - bzf;
}

// count + per-particle rank within its cell (atomicAdd's return value)
__global__ void __launch_bounds__(256)
count_kernel(const float* __restrict__ x, int* __restrict__ cell_count,
             int* __restrict__ rank, int N) {
    int n = blockIdx.x*256 + threadIdx.x;
    if (n >= N) return;
    int bi, bj, bk; float f0, f1, f2;
    base_from_A(x[3*n+0]*c_INV_DX, x[3*n+1]*c_INV_DX, x[3*n+2]*c_INV_DX,
                bi, bj, bk, f0, f1, f2);
    rank[n] = atomicAdd(&cell_count[(bi*NG + bj)*NG + bk], 1);
}

// ---- scan stage A: per-block (256 elems) reduction -> partial[block] ----
__global__ void __launch_bounds__(256)
scan_partial_kernel(const int* __restrict__ count, int* __restrict__ partial) {
    __shared__ int red[256];
    int t = threadIdx.x;
    red[t] = count[blockIdx.x*256 + t];
    __syncthreads();
    for (int off = 128; off > 0; off >>= 1) {
        if (t < off) red[t] += red[t+off];
        __syncthreads();
    }
    if (t == 0) partial[blockIdx.x] = red[0];
}

// ---- scan stage B: exclusive scan of 8192 partials, 1 block, 256x32 ----
__global__ void __launch_bounds__(256)
scan_partials_kernel(int* __restrict__ partial) {
    __shared__ int part[256];
    int t = threadIdx.x;
    int base = t*32;
    int local[32];
    int s = 0;
    #pragma unroll
    for (int i = 0; i < 32; ++i) { local[i] = s; s += partial[base+i]; }
    part[t] = s;
    __syncthreads();
    for (int off = 1; off < 256; off <<= 1) {
        int v = (t >= off) ? part[t-off] : 0;
        __syncthreads();
        part[t] += v;
        __syncthreads();
    }
    int prev = (t == 0) ? 0 : part[t-1];
    #pragma unroll
    for (int i = 0; i < 32; ++i) partial[base+i] = prev + local[i];
}

// ---- scan stage C: block-level exclusive scan + partial base -> offset ----
__global__ void __launch_bounds__(256)
scan_final_kernel(const int* __restrict__ count, const int* __restrict__ partial,
                  int* __restrict__ offset) {
    __shared__ int part[256];
    int t = threadIdx.x;
    int i = blockIdx.x*256 + t;
    int c = count[i];
    part[t] = c;
    __syncthreads();
    for (int off = 1; off < 256; off <<= 1) {
        int v = (t >= off) ? part[t-off] : 0;
        __syncthreads();
        part[t] += v;
        __syncthreads();
    }
    int base = partial[blockIdx.x];
    offset[i] = base + part[t] - c;
    if (i == G3-1) offset[G3] = base + part[t];
}

// ---------------- pre-pass: all per-particle math, coalesced reads ----------------
__global__ void __launch_bounds__(256)
pre_kernel(const float* __restrict__ x, const float* __restrict__ v,
           const float* __restrict__ Cin, const float* __restrict__ Fin,
           const float* __restrict__ Jp_in, const int* __restrict__ material,
           const int* __restrict__ offset, const int* __restrict__ rank,
           PRec* __restrict__ rec, float* __restrict__ out, int N) {
    int n = blockIdx.x*256 + threadIdx.x;
    if (n >= N) return;

    float A0 = x[3*n+0]*c_INV_DX, A1 = x[3*n+1]*c_INV_DX, A2 = x[3*n+2]*c_INV_DX;
    int bi, bj, bk; float f0, f1, f2;
    base_from_A(A0, A1, A2, bi, bj, bk, f0, f1, f2);

    float Cm[9], Fm[9];
    #pragma unroll
    for (int i = 0; i < 9; ++i) { Cm[i] = Cin[9*n+i]; Fm[i] = Fin[9*n+i]; }

    // Fn = (I + DT*C) @ F
    float Fn[9];
    #pragma unroll
    for (int i = 0; i < 3; ++i)
        #pragma unroll
        for (int k = 0; k < 3; ++k) {
            float acc = Fm[i*3+k];
            #pragma unroll
            for (int j = 0; j < 3; ++j) acc += DT * Cm[i*3+j] * Fm[j*3+k];
            Fn[i*3+k] = acc;
        }

    float Jp = Jp_in[n];
    int mat = material[n];
    float h = expf(10.0f*(1.0f - Jp));
    h = fminf(fmaxf(h, 0.1f), 5.0f);
    if (mat == 1) h = 0.3f;
    float mu = (mat == 0) ? 0.0f : MU0*h;
    float la = LAM0*h;

    float U[9], V[9], sv[3];
    svd3(Fn, U, sv, V);

    float J = 1.0f;
    float sig[3];
    #pragma unroll
    for (int d = 0; d < 2; ++d) {
        float s = sv[d];
        float ns = (mat == 2) ? fminf(fmaxf(s, 1.0f-0.025f), 1.0f+0.0045f) : s;
        Jp = Jp * s / ns;
        sig[d] = ns;
        J *= ns;
    }
    sig[2] = sv[2];

    if (mat == 0) {
        float sj = sqrtf(J);
        Fn[0]=sj; Fn[1]=0; Fn[2]=0; Fn[3]=0; Fn[4]=sj; Fn[5]=0; Fn[6]=0; Fn[7]=0; Fn[8]=sj;
    } else if (mat == 2) {
        #pragma unroll
        for (int i = 0; i < 3; ++i)
            #pragma unroll
            for (int k = 0; k < 3; ++k) {
                float acc = 0.f;
                #pragma unroll
                for (int j = 0; j < 3; ++j) acc += U[i*3+j]*sig[j]*V[k*3+j];
                Fn[i*3+k] = acc;
            }
    }

    float R[9];
    #pragma unroll
    for (int i = 0; i < 3; ++i)
        #pragma unroll
        for (int k = 0; k < 3; ++k) {
            float acc = 0.f;
            #pragma unroll
            for (int j = 0; j < 3; ++j) acc += U[i*3+j]*V[k*3+j];
            R[i*3+k] = acc;
        }

    float press = la * J * (J - 1.0f);
    float scale = -DT * P_VOL * 4.0f * c_INV_DX * c_INV_DX;
    float aff[9];
    #pragma unroll
    for (int i = 0; i < 3; ++i)
        #pragma unroll
        for (int k = 0; k < 3; ++k) {
            float acc = 0.f;
            #pragma unroll
            for (int j = 0; j < 3; ++j) acc += (Fn[i*3+j]-R[i*3+j])*Fn[k*3+j];
            acc = 2.0f*mu*acc;
            if (i == k) acc += press;
            aff[i*3+k] = scale*acc + P_MASS*Cm[i*3+k];
        }

    float* po = out + (size_t)n*25;
    po[6] = Jp;
    #pragma unroll
    for (int i = 0; i < 9; ++i) po[7+i] = Fn[i];

    // cell-bucket slot (rank captured by count_kernel's atomicAdd)
    int cell = (bi*NG + bj)*NG + bk;
    int pos = offset[cell] + rank[n];

    float4* rp = (float4*)&rec[pos];
    rp[0] = make_float4(A0, A1, A2, __int_as_float(n));
    rp[1] = make_float4(aff[0], aff[1], aff[2], aff[3]);
    rp[2] = make_float4(aff[4], aff[5], aff[6], aff[7]);
    rp[3] = make_float4(aff[8], P_MASS*v[3*n+0], P_MASS*v[3*n+1], P_MASS*v[3*n+2]);
}

// ------- fused P2G-gather + grid update: one thread per 4 z-cells, NO atomics ----
// v4: single fused particle loop over all 9 (bi,bj) ranges.
//   Round-3 analysis: 9 separate per-column loops each run to the wave-max of
//   per-lane counts (sum of 9 straggler taxes, ~9x issue waste vs useful work).
//   The body is (di,dj)-independent (weights use absolute coords), so the 9
//   ranges concatenate into ONE per-lane stream: one wave-max total.
//   Range (s,e) pairs live in LDS [range][tid] (bank = tid&31, conflict-free,
//   no barriers needed) to avoid scratch from runtime-indexed register arrays.
//   Accumulation order per cell is unchanged -> fp-identical results.
__global__ void __launch_bounds__(128)
grid_gather_kernel(const PRec* __restrict__ rec, const int* __restrict__ offset,
                   float4* __restrict__ grid, const float* __restrict__ gravity,
                   const float* __restrict__ attr_s, const float* __restrict__ attr_p) {
    __shared__ int rS[9*128];
    __shared__ int rE[9*128];
    int tid = threadIdx.x;
    int g4 = blockIdx.x*128 + tid;   // quad index (G3/4 total)
    int zq = g4 & 31;
    int gj = (g4 >> 5) & (NG-1);
    int gi = g4 >> 12;
    int zlo = zq*4;

    int bk0 = max(zlo-2, 0), bk1 = min(zlo+3, NG-3);

    // fetch all 9 column ranges (18 independent loads in flight) -> LDS table
    bool any = false;
    #pragma unroll
    for (int di = 0; di < 3; ++di) {
        int bi = gi - 2 + di;
        bool vi = (bi >= 0) && (bi <= NG-3);
        #pragma unroll
        for (int dj = 0; dj < 3; ++dj) {
            int bj = gj - 2 + dj;
            bool vj = vi && (bj >= 0) && (bj <= NG-3);
            int col = ((vj ? bi : 0)*NG + (vj ? bj : 0))*NG;
            int s = vj ? offset[col + bk0]     : 0;
            int e = vj ? offset[col + bk1 + 1] : 0;
            rS[(di*3+dj)*128 + tid] = s;
            rE[(di*3+dj)*128 + tid] = e;
            if (s < e) any = true;
        }
    }

    // quads with zero visits are never read by g2p (any cell g2p reads has a
    // member particle, and member particles lie in this quad's bucket window)
    if (!any) return;

    float ax[4], ay[4], az[4], mm[4];
    #pragma unroll
    for (int h = 0; h < 4; ++h) { ax[h]=0.f; ay[h]=0.f; az[h]=0.f; mm[h]=0.f; }

    float gif = (float)gi, gjf = (float)gj, z0f = (float)zlo;

    // fused stream over the 9 ranges (per-lane private advance)
    int ridx = 0;
    int p = rS[tid], e = rE[tid];
    while (p >= e) {
        if (++ridx >= 9) break;
        p = rS[ridx*128 + tid]; e = rE[ridx*128 + tid];
    }
    while (ridx < 9) {
        const float4* rp = (const float4*)&rec[p];
        float4 r0 = rp[0];
        float4 r1 = rp[1];
        float4 r2 = rp[2];
        float4 r3 = rp[3];

        // symmetric quadratic B-spline N(u), u = cell - A (fp-exact vs ref)
        float ux = gif - r0.x;
        float aux = fabsf(ux);
        float tx = 1.5f - aux;
        float nx = (aux < 0.5f) ? (0.75f - ux*ux) : (0.5f*tx*tx);
        float uy = gjf - r0.y;
        float auy = fabsf(uy);
        float ty = 1.5f - auy;
        float ny = (auy < 0.5f) ? (0.75f - uy*uy) : (0.5f*ty*ty);
        float wgt = nx*ny;                 // reference: x,y weights only

        float uz0 = z0f - r0.z;
        float dpx = ux*c_DX, dpy = uy*c_DX, dpz0 = uz0*c_DX;
        float cx = r3.y + r1.x*dpx + r1.y*dpy + r1.z*dpz0;
        float cy = r3.z + r1.w*dpx + r2.x*dpy + r2.y*dpz0;
        float cz = r3.w + r2.z*dpx + r2.w*dpy + r3.x*dpz0;
        float ix = r1.z*c_DX, iy = r2.y*c_DX, iz = r3.x*c_DX;

        #pragma unroll
        for (int h = 0; h < 4; ++h) {
            float uz = uz0 + (float)h;
            // membership mask: uz in (-1.5, 1.5]
            float w = (uz > -1.5f && uz <= 1.5f) ? wgt : 0.f;
            ax[h] += w*cx; ay[h] += w*cy; az[h] += w*cz; mm[h] += w*P_MASS;
            cx += ix; cy += iy; cz += iz;
        }

        ++p;
        while (p >= e) {
            if (++ridx >= 9) break;
            p = rS[ridx*128 + tid]; e = rE[ridx*128 + tid];
        }
    }

    float gx = DT*gravity[0]*30.0f, gy = DT*gravity[1]*30.0f, gz = DT*gravity[2]*30.0f;
    float apx = attr_p[0], apy = attr_p[1], apz = attr_p[2];
    float as  = attr_s[0] * DT * 100.0f;

    int gidx = (gi*NG + gj)*NG + zlo;
    #pragma unroll
    for (int h = 0; h < 4; ++h) {
        float m = mm[h];
        int gk = zlo + h;
        float gvx = 0.f, gvy = 0.f, gvz = 0.f;
        if (m > 0.f) {
            float inv = 1.0f/m;
            gvx = ax[h]*inv + gx; gvy = ay[h]*inv + gy; gvz = az[h]*inv + gz;
            float dx_ = apx - c_DX*(float)gi;
            float dy_ = apy - c_DX*(float)gj;
            float dz_ = apz - c_DX*(float)gk;
            float nrm = sqrtf(dx_*dx_ + dy_*dy_ + dz_*dz_);
            float sc = as / (0.01f + nrm);
            gvx += dx_*sc; gvy += dy_*sc; gvz += dz_*sc;
            if (gi < 3      && gvx < 0.f) gvx = 0.f;
            if (gi > NG-3   && gvx > 0.f) gvx = 0.f;
            if (gj < 3      && gvy < 0.f) gvy = 0.f;
            if (gj > NG-3   && gvy > 0.f) gvy = 0.f;
            // z unconstrained (matches reference)
        }
        grid[gidx + h] = make_float4(gvx, gvy, gvz, m);
    }
}

// ---------------- G2P (cell-sorted order, coalesced record reads) ----------------
__global__ void __launch_bounds__(256)
g2p_kernel(const PRec* __restrict__ rec, const float4* __restrict__ grid,
           float* __restrict__ out, int N) {
    int gid = blockIdx.x * 256 + threadIdx.x;
    if (gid >= N) return;

    float4 r0 = rec[gid].r0;
    float A0 = r0.x, A1 = r0.y, A2 = r0.z;
    int n = __float_as_int(r0.w);

    int bi, bj, bk; float fx0, fx1, fx2;
    base_from_A(A0, A1, A2, bi, bj, bk, fx0, fx1, fx2);

    float wx[3], wy[3];
    wx[0] = 0.5f*(1.5f-fx0)*(1.5f-fx0); wx[1] = 0.75f-(fx0-1.f)*(fx0-1.f); wx[2] = 0.5f*(fx0-0.5f)*(fx0-0.5f);
    wy[0] = 0.5f*(1.5f-fx1)*(1.5f-fx1); wy[1] = 0.75f-(fx1-1.f)*(fx1-1.f); wy[2] = 0.5f*(fx1-0.5f)*(fx1-0.5f);

    float nvx = 0.f, nvy = 0.f, nvz = 0.f;
    float nC[9];
    #pragma unroll
    for (int i = 0; i < 9; ++i) nC[i] = 0.f;

    #pragma unroll
    for (int i = 0; i < 3; ++i) {
        float dpx = (float)i - fx0;
        #pragma unroll
        for (int j = 0; j < 3; ++j) {
            float wgt = wx[i]*wy[j];
            float dpy = (float)j - fx1;
            int cell0 = ((bi+i)*NG + (bj+j))*NG + bk;
            #pragma unroll
            for (int k = 0; k < 3; ++k) {
                float dpz = (float)k - fx2;
                float4 gv = grid[cell0 + k];
                float wgx = wgt*gv.x, wgy = wgt*gv.y, wgz = wgt*gv.z;
                nvx += wgx; nvy += wgy; nvz += wgz;
                nC[0] += wgx*dpx; nC[1] += wgx*dpy; nC[2] += wgx*dpz;
                nC[3] += wgy*dpx; nC[4] += wgy*dpy; nC[5] += wgy*dpz;
                nC[6] += wgz*dpx; nC[7] += wgz*dpy; nC[8] += wgz*dpz;
            }
        }
    }

    float* po = out + (size_t)n*25;
    float px = A0*c_DX, py = A1*c_DX, pz = A2*c_DX;   // exact reconstruction
    po[0] = px + DT*nvx;
    po[1] = py + DT*nvy;
    po[2] = pz + DT*nvz;
    po[3] = nvx; po[4] = nvy; po[5] = nvz;
    float s4 = 4.0f*c_INV_DX;
    #pragma unroll
    for (int i = 0; i < 9; ++i) po[16+i] = s4*nC[i];
}

extern "C" void kernel_launch(void* const* d_in, const int* in_sizes, int n_in,
                              void* d_out, int out_size, void* d_ws, size_t ws_size,
                              hipStream_t stream) {
    const float* x        = (const float*)d_in[0];
    const float* v        = (const float*)d_in[1];
    const float* C        = (const float*)d_in[2];
    const float* F        = (const float*)d_in[3];
    const float* Jp       = (const float*)d_in[4];
    const float* gravity  = (const float*)d_in[5];
    const float* attr_s   = (const float*)d_in[6];
    const float* attr_p   = (const float*)d_in[7];
    const int*   material = (const int*)d_in[8];
    float* out = (float*)d_out;
    int N = in_sizes[0] / 3;

    // workspace: [count G3] (zeroed) [offset G3+1][partial][rank N][grid][rec]
    char* ws = (char*)d_ws;
    size_t o = 0;
    int* cell_count = (int*)(ws + o);      o += (size_t)G3*sizeof(int);
    size_t zero_bytes = o;
    int* offset     = (int*)(ws + o);      o += ((size_t)G3+1)*sizeof(int);
    int* partial    = (int*)(ws + o);      o += (size_t)NSCAN_BLOCKS*sizeof(int);
    int* rank       = (int*)(ws + o);      o += (size_t)N*sizeof(int);
    o = (o + 127) & ~(size_t)127;
    float4* grid    = (float4*)(ws + o);   o += (size_t)G3*sizeof(float4);
    PRec* rec       = (PRec*)(ws + o);     o += (size_t)N*sizeof(PRec);

    hipMemsetAsync(d_ws, 0, zero_bytes, stream);

    int pblocks = (N + 255) / 256;
    count_kernel<<<pblocks, 256, 0, stream>>>(x, cell_count, rank, N);
    scan_partial_kernel<<<NSCAN_BLOCKS, 256, 0, stream>>>(cell_count, partial);
    scan_partials_kernel<<<1, 256, 0, stream>>>(partial);
    scan_final_kernel<<<NSCAN_BLOCKS, 256, 0, stream>>>(cell_count, partial, offset);
    pre_kernel<<<pblocks, 256, 0, stream>>>(x, v, C, F, Jp, material,
                                            offset, rank, rec, out, N);
    grid_gather_kernel<<<G3/512, 128, 0, stream>>>(rec, offset, grid,
                                                   gravity, attr_s, attr_p);
    g2p_kernel<<<pblocks, 256, 0, stream>>>(rec, grid, out, N);
}

// Round 5
// 260.626 us; speedup vs baseline: 2.1218x; 1.0003x over previous
//
#include <hip/hip_runtime.h>

#define NG 128
#define G3 (NG*NG*NG)
#define NSCAN_BLOCKS (G3/256)   // 8192

__device__ __constant__ const float c_DX      = 1.0f/128.0f;
__device__ __constant__ const float c_INV_DX  = 128.0f;

#define DT      1e-4f
#define P_VOL   ((1.0f/256.0f)*(1.0f/256.0f))
#define P_MASS  P_VOL
#define MU0     (5000.0f/(2.0f*1.2f))
#define LAM0    (5000.0f*0.2f/(1.2f*0.6f))

// 64-byte packed particle record, stored in cell-bucket order
// r0 = {A0, A1, A2, particle_id}   A = x*INV_DX (absolute grid coord; exact)
// r1 = {aff0..3}, r2 = {aff4..7}, r3 = {aff8, mv0, mv1, mv2}
struct __align__(16) PRec {
    float4 r0, r1, r2, r3;
};

// ---------------- 3x3 SVD via Jacobi on A^T A ----------------
__device__ inline void jacobi_rot(float S[3][3], float V[3][3], int p, int q) {
    float apq = S[p][q];
    if (fabsf(apq) < 1e-24f) return;
    float tau = (S[q][q] - S[p][p]) / (2.0f * apq);
    float t = copysignf(1.0f, tau) / (fabsf(tau) + sqrtf(1.0f + tau*tau));
    float c = rsqrtf(1.0f + t*t);
    float sn = t * c;
    #pragma unroll
    for (int k = 0; k < 3; ++k) {
        float Spk = S[p][k], Sqk = S[q][k];
        S[p][k] = c*Spk - sn*Sqk;
        S[q][k] = sn*Spk + c*Sqk;
    }
    #pragma unroll
    for (int k = 0; k < 3; ++k) {
        float Skp = S[k][p], Skq = S[k][q];
        S[k][p] = c*Skp - sn*Skq;
        S[k][q] = sn*Skp + c*Skq;
    }
    #pragma unroll
    for (int k = 0; k < 3; ++k) {
        float Vkp = V[k][p], Vkq = V[k][q];
        V[k][p] = c*Vkp - sn*Vkq;
        V[k][q] = sn*Vkp + c*Vkq;
    }
}

__device__ inline void svd3(const float A[9], float U[9], float sv[3], float V[9]) {
    float S[3][3];
    #pragma unroll
    for (int i = 0; i < 3; ++i)
        #pragma unroll
        for (int j = 0; j < 3; ++j) {
            float acc = 0.f;
            #pragma unroll
            for (int k = 0; k < 3; ++k) acc += A[k*3+i]*A[k*3+j];
            S[i][j] = acc;
        }
    float Vm[3][3] = {{1.f,0.f,0.f},{0.f,1.f,0.f},{0.f,0.f,1.f}};
    #pragma unroll
    for (int sweep = 0; sweep < 4; ++sweep) {
        jacobi_rot(S, Vm, 0, 1);
        jacobi_rot(S, Vm, 0, 2);
        jacobi_rot(S, Vm, 1, 2);
    }
    float lam[3] = {S[0][0], S[1][1], S[2][2]};
    int i0 = 0, i1 = 1, i2 = 2, t;
    if (lam[i0] < lam[i1]) { t = i0; i0 = i1; i1 = t; }
    if (lam[i0] < lam[i2]) { t = i0; i0 = i2; i2 = t; }
    if (lam[i1] < lam[i2]) { t = i1; i1 = i2; i2 = t; }
    int ord[3] = {i0, i1, i2};
    #pragma unroll
    for (int c = 0; c < 3; ++c) {
        int s_ = ord[c];
        float l = fmaxf(lam[s_], 0.f);
        float sval = sqrtf(l);
        sv[c] = sval;
        float v0 = Vm[0][s_], v1 = Vm[1][s_], v2 = Vm[2][s_];
        V[0*3+c] = v0; V[1*3+c] = v1; V[2*3+c] = v2;
        float inv = (sval > 1e-12f) ? 1.0f/sval : 0.f;
        U[0*3+c] = (A[0]*v0 + A[1]*v1 + A[2]*v2)*inv;
        U[1*3+c] = (A[3]*v0 + A[4]*v1 + A[5]*v2)*inv;
        U[2*3+c] = (A[6]*v0 + A[7]*v1 + A[8]*v2)*inv;
    }
}

// ---------------- binning helpers ----------------
// from absolute grid coord A: base cell + frac (all fp-exact)
__device__ inline void base_from_A(float A0, float A1, float A2,
                                   int& bi, int& bj, int& bk,
                                   float& fx0, float& fx1, float& fx2) {
    float bxf = floorf(A0 - 0.5f);
    float byf = floorf(A1 - 0.5f);
    float bzf = floorf(A2 - 0.5f);
    bi = (int)bxf; bj = (int)byf; bk = (int)bzf;
    bi = min(max(bi, 0), NG-3); bj = min(max(bj, 0), NG-3); bk = min(max(bk, 0), NG-3);
    fx0 = A0 - bxf;
    fx1 = A1 - byf;
    fx2 = A2 - bzf;
}

// count + per-particle rank within its cell (atomicAdd's return value)
__global__ void __launch_bounds__(256)
count_kernel(const float* __restrict__ x, int* __restrict__ cell_count,
             int* __restrict__ rank, int N) {
    int n = blockIdx.x*256 + threadIdx.x;
    if (n >= N) return;
    int bi, bj, bk; float f0, f1, f2;
    base_from_A(x[3*n+0]*c_INV_DX, x[3*n+1]*c_INV_DX, x[3*n+2]*c_INV_DX,
                bi, bj, bk, f0, f1, f2);
    rank[n] = atomicAdd(&cell_count[(bi*NG + bj)*NG + bk], 1);
}

// ---- scan stage A: per-block (256 elems) reduction -> partial[block] ----
__global__ void __launch_bounds__(256)
scan_partial_kernel(const int* __restrict__ count, int* __restrict__ partial) {
    __shared__ int red[256];
    int t = threadIdx.x;
    red[t] = count[blockIdx.x*256 + t];
    __syncthreads();
    for (int off = 128; off > 0; off >>= 1) {
        if (t < off) red[t] += red[t+off];
        __syncthreads();
    }
    if (t == 0) partial[blockIdx.x] = red[0];
}

// ---- scan stage B: exclusive scan of 8192 partials, 1 block, 256x32 ----
__global__ void __launch_bounds__(256)
scan_partials_kernel(int* __restrict__ partial) {
    __shared__ int part[256];
    int t = threadIdx.x;
    int base = t*32;
    int local[32];
    int s = 0;
    #pragma unroll
    for (int i = 0; i < 32; ++i) { local[i] = s; s += partial[base+i]; }
    part[t] = s;
    __syncthreads();
    for (int off = 1; off < 256; off <<= 1) {
        int v = (t >= off) ? part[t-off] : 0;
        __syncthreads();
        part[t] += v;
        __syncthreads();
    }
    int prev = (t == 0) ? 0 : part[t-1];
    #pragma unroll
    for (int i = 0; i < 32; ++i) partial[base+i] = prev + local[i];
}

// ---- scan stage C: block-level exclusive scan + partial base -> offset ----
__global__ void __launch_bounds__(256)
scan_final_kernel(const int* __restrict__ count, const int* __restrict__ partial,
                  int* __restrict__ offset) {
    __shared__ int part[256];
    int t = threadIdx.x;
    int i = blockIdx.x*256 + t;
    int c = count[i];
    part[t] = c;
    __syncthreads();
    for (int off = 1; off < 256; off <<= 1) {
        int v = (t >= off) ? part[t-off] : 0;
        __syncthreads();
        part[t] += v;
        __syncthreads();
    }
    int base = partial[blockIdx.x];
    offset[i] = base + part[t] - c;
    if (i == G3-1) offset[G3] = base + part[t];
}

// ---------------- pre-pass: all per-particle math, coalesced reads ----------------
__global__ void __launch_bounds__(256)
pre_kernel(const float* __restrict__ x, const float* __restrict__ v,
           const float* __restrict__ Cin, const float* __restrict__ Fin,
           const float* __restrict__ Jp_in, const int* __restrict__ material,
           const int* __restrict__ offset, const int* __restrict__ rank,
           PRec* __restrict__ rec, float* __restrict__ out, int N) {
    int n = blockIdx.x*256 + threadIdx.x;
    if (n >= N) return;

    float A0 = x[3*n+0]*c_INV_DX, A1 = x[3*n+1]*c_INV_DX, A2 = x[3*n+2]*c_INV_DX;
    int bi, bj, bk; float f0, f1, f2;
    base_from_A(A0, A1, A2, bi, bj, bk, f0, f1, f2);

    float Cm[9], Fm[9];
    #pragma unroll
    for (int i = 0; i < 9; ++i) { Cm[i] = Cin[9*n+i]; Fm[i] = Fin[9*n+i]; }

    // Fn = (I + DT*C) @ F
    float Fn[9];
    #pragma unroll
    for (int i = 0; i < 3; ++i)
        #pragma unroll
        for (int k = 0; k < 3; ++k) {
            float acc = Fm[i*3+k];
            #pragma unroll
            for (int j = 0; j < 3; ++j) acc += DT * Cm[i*3+j] * Fm[j*3+k];
            Fn[i*3+k] = acc;
        }

    float Jp = Jp_in[n];
    int mat = material[n];
    float h = expf(10.0f*(1.0f - Jp));
    h = fminf(fmaxf(h, 0.1f), 5.0f);
    if (mat == 1) h = 0.3f;
    float mu = (mat == 0) ? 0.0f : MU0*h;
    float la = LAM0*h;

    float U[9], V[9], sv[3];
    svd3(Fn, U, sv, V);

    float J = 1.0f;
    float sig[3];
    #pragma unroll
    for (int d = 0; d < 2; ++d) {
        float s = sv[d];
        float ns = (mat == 2) ? fminf(fmaxf(s, 1.0f-0.025f), 1.0f+0.0045f) : s;
        Jp = Jp * s / ns;
        sig[d] = ns;
        J *= ns;
    }
    sig[2] = sv[2];

    if (mat == 0) {
        float sj = sqrtf(J);
        Fn[0]=sj; Fn[1]=0; Fn[2]=0; Fn[3]=0; Fn[4]=sj; Fn[5]=0; Fn[6]=0; Fn[7]=0; Fn[8]=sj;
    } else if (mat == 2) {
        #pragma unroll
        for (int i = 0; i < 3; ++i)
            #pragma unroll
            for (int k = 0; k < 3; ++k) {
                float acc = 0.f;
                #pragma unroll
                for (int j = 0; j < 3; ++j) acc += U[i*3+j]*sig[j]*V[k*3+j];
                Fn[i*3+k] = acc;
            }
    }

    float R[9];
    #pragma unroll
    for (int i = 0; i < 3; ++i)
        #pragma unroll
        for (int k = 0; k < 3; ++k) {
            float acc = 0.f;
            #pragma unroll
            for (int j = 0; j < 3; ++j) acc += U[i*3+j]*V[k*3+j];
            R[i*3+k] = acc;
        }

    float press = la * J * (J - 1.0f);
    float scale = -DT * P_VOL * 4.0f * c_INV_DX * c_INV_DX;
    float aff[9];
    #pragma unroll
    for (int i = 0; i < 3; ++i)
        #pragma unroll
        for (int k = 0; k < 3; ++k) {
            float acc = 0.f;
            #pragma unroll
            for (int j = 0; j < 3; ++j) acc += (Fn[i*3+j]-R[i*3+j])*Fn[k*3+j];
            acc = 2.0f*mu*acc;
            if (i == k) acc += press;
            aff[i*3+k] = scale*acc + P_MASS*Cm[i*3+k];
        }

    float* po = out + (size_t)n*25;
    po[6] = Jp;
    #pragma unroll
    for (int i = 0; i < 9; ++i) po[7+i] = Fn[i];

    // cell-bucket slot (rank captured by count_kernel's atomicAdd)
    int cell = (bi*NG + bj)*NG + bk;
    int pos = offset[cell] + rank[n];

    float4* rp = (float4*)&rec[pos];
    rp[0] = make_float4(A0, A1, A2, __int_as_float(n));
    rp[1] = make_float4(aff[0], aff[1], aff[2], aff[3]);
    rp[2] = make_float4(aff[4], aff[5], aff[6], aff[7]);
    rp[3] = make_float4(aff[8], P_MASS*v[3*n+0], P_MASS*v[3*n+1], P_MASS*v[3*n+2]);
}

// ------- fused P2G-gather + grid update: one thread per 4 z-cells, NO atomics ----
// v5: v4's fused single stream + 1-deep software pipeline.
//   v4 data: 64 us, VALUBusy 40% -> ~60% of time is exposed record-load
//   latency (advance -> addr -> 64B load -> body is a serial chain).
//   The advance has NO data dependence on the loaded record, so we advance
//   and issue the NEXT record's loads BEFORE running the current body;
//   the s_waitcnt moves to the end-of-body register copy. fp-identical
//   accumulation order.
__global__ void __launch_bounds__(128)
grid_gather_kernel(const PRec* __restrict__ rec, const int* __restrict__ offset,
                   float4* __restrict__ grid, const float* __restrict__ gravity,
                   const float* __restrict__ attr_s, const float* __restrict__ attr_p) {
    __shared__ int rS[9*128];
    __shared__ int rE[9*128];
    int tid = threadIdx.x;
    int g4 = blockIdx.x*128 + tid;   // quad index (G3/4 total)
    int zq = g4 & 31;
    int gj = (g4 >> 5) & (NG-1);
    int gi = g4 >> 12;
    int zlo = zq*4;

    int bk0 = max(zlo-2, 0), bk1 = min(zlo+3, NG-3);

    // fetch all 9 column ranges (18 independent loads in flight) -> LDS table
    bool any = false;
    #pragma unroll
    for (int di = 0; di < 3; ++di) {
        int bi = gi - 2 + di;
        bool vi = (bi >= 0) && (bi <= NG-3);
        #pragma unroll
        for (int dj = 0; dj < 3; ++dj) {
            int bj = gj - 2 + dj;
            bool vj = vi && (bj >= 0) && (bj <= NG-3);
            int col = ((vj ? bi : 0)*NG + (vj ? bj : 0))*NG;
            int s = vj ? offset[col + bk0]     : 0;
            int e = vj ? offset[col + bk1 + 1] : 0;
            rS[(di*3+dj)*128 + tid] = s;
            rE[(di*3+dj)*128 + tid] = e;
            if (s < e) any = true;
        }
    }

    // quads with zero visits are never read by g2p (any cell g2p reads has a
    // member particle, and member particles lie in this quad's bucket window)
    if (!any) return;

    float ax[4], ay[4], az[4], mm[4];
    #pragma unroll
    for (int h = 0; h < 4; ++h) { ax[h]=0.f; ay[h]=0.f; az[h]=0.f; mm[h]=0.f; }

    float gif = (float)gi, gjf = (float)gj, z0f = (float)zlo;

    // ---- software-pipelined fused stream over the 9 ranges ----
    // position state
    int ridx = 0;
    int p = rS[tid], e = rE[tid];
    while (p >= e) {
        if (++ridx >= 9) break;
        p = rS[ridx*128 + tid]; e = rE[ridx*128 + tid];
    }

    // prime: load current record
    float4 c0, c1, c2, c3;
    {
        const float4* rp = (const float4*)&rec[(ridx < 9) ? p : 0];
        c0 = rp[0]; c1 = rp[1]; c2 = rp[2]; c3 = rp[3];
    }

    while (ridx < 9) {
        // advance to next position (no dependence on record data)
        int np = p + 1, nr = ridx, ne = e;
        while (np >= ne) {
            if (++nr >= 9) break;
            np = rS[nr*128 + tid]; ne = rE[nr*128 + tid];
        }

        // issue NEXT record's loads now; they fly during the body below
        const float4* rp = (const float4*)&rec[(nr < 9) ? np : 0];
        float4 n0 = rp[0], n1 = rp[1], n2 = rp[2], n3 = rp[3];

        // ---- body on current record (c0..c3) ----
        // symmetric quadratic B-spline N(u), u = cell - A (fp-exact vs ref)
        float ux = gif - c0.x;
        float aux = fabsf(ux);
        float tx = 1.5f - aux;
        float nx = (aux < 0.5f) ? (0.75f - ux*ux) : (0.5f*tx*tx);
        float uy = gjf - c0.y;
        float auy = fabsf(uy);
        float ty = 1.5f - auy;
        float ny = (auy < 0.5f) ? (0.75f - uy*uy) : (0.5f*ty*ty);
        float wgt = nx*ny;                 // reference: x,y weights only

        float uz0 = z0f - c0.z;
        float dpx = ux*c_DX, dpy = uy*c_DX, dpz0 = uz0*c_DX;
        float cx = c3.y + c1.x*dpx + c1.y*dpy + c1.z*dpz0;
        float cy = c3.z + c1.w*dpx + c2.x*dpy + c2.y*dpz0;
        float cz = c3.w + c2.z*dpx + c2.w*dpy + c3.x*dpz0;
        float ix = c1.z*c_DX, iy = c2.y*c_DX, iz = c3.x*c_DX;

        #pragma unroll
        for (int h = 0; h < 4; ++h) {
            float uz = uz0 + (float)h;
            // membership mask: uz in (-1.5, 1.5]
            float w = (uz > -1.5f && uz <= 1.5f) ? wgt : 0.f;
            ax[h] += w*cx; ay[h] += w*cy; az[h] += w*cz; mm[h] += w*P_MASS;
            cx += ix; cy += iy; cz += iz;
        }

        // rotate pipeline
        p = np; ridx = nr; e = ne;
        c0 = n0; c1 = n1; c2 = n2; c3 = n3;
    }

    float gx = DT*gravity[0]*30.0f, gy = DT*gravity[1]*30.0f, gz = DT*gravity[2]*30.0f;
    float apx = attr_p[0], apy = attr_p[1], apz = attr_p[2];
    float as  = attr_s[0] * DT * 100.0f;

    int gidx = (gi*NG + gj)*NG + zlo;
    #pragma unroll
    for (int h = 0; h < 4; ++h) {
        float m = mm[h];
        int gk = zlo + h;
        float gvx = 0.f, gvy = 0.f, gvz = 0.f;
        if (m > 0.f) {
            float inv = 1.0f/m;
            gvx = ax[h]*inv + gx; gvy = ay[h]*inv + gy; gvz = az[h]*inv + gz;
            float dx_ = apx - c_DX*(float)gi;
            float dy_ = apy - c_DX*(float)gj;
            float dz_ = apz - c_DX*(float)gk;
            float nrm = sqrtf(dx_*dx_ + dy_*dy_ + dz_*dz_);
            float sc = as / (0.01f + nrm);
            gvx += dx_*sc; gvy += dy_*sc; gvz += dz_*sc;
            if (gi < 3      && gvx < 0.f) gvx = 0.f;
            if (gi > NG-3   && gvx > 0.f) gvx = 0.f;
            if (gj < 3      && gvy < 0.f) gvy = 0.f;
            if (gj > NG-3   && gvy > 0.f) gvy = 0.f;
            // z unconstrained (matches reference)
        }
        grid[gidx + h] = make_float4(gvx, gvy, gvz, m);
    }
}

// ---------------- G2P (cell-sorted order, coalesced record reads) ----------------
__global__ void __launch_bounds__(256)
g2p_kernel(const PRec* __restrict__ rec, const float4* __restrict__ grid,
           float* __restrict__ out, int N) {
    int gid = blockIdx.x * 256 + threadIdx.x;
    if (gid >= N) return;

    float4 r0 = rec[gid].r0;
    float A0 = r0.x, A1 = r0.y, A2 = r0.z;
    int n = __float_as_int(r0.w);

    int bi, bj, bk; float fx0, fx1, fx2;
    base_from_A(A0, A1, A2, bi, bj, bk, fx0, fx1, fx2);

    float wx[3], wy[3];
    wx[0] = 0.5f*(1.5f-fx0)*(1.5f-fx0); wx[1] = 0.75f-(fx0-1.f)*(fx0-1.f); wx[2] = 0.5f*(fx0-0.5f)*(fx0-0.5f);
    wy[0] = 0.5f*(1.5f-fx1)*(1.5f-fx1); wy[1] = 0.75f-(fx1-1.f)*(fx1-1.f); wy[2] = 0.5f*(fx1-0.5f)*(fx1-0.5f);

    float nvx = 0.f, nvy = 0.f, nvz = 0.f;
    float nC[9];
    #pragma unroll
    for (int i = 0; i < 9; ++i) nC[i] = 0.f;

    #pragma unroll
    for (int i = 0; i < 3; ++i) {
        float dpx = (float)i - fx0;
        #pragma unroll
        for (int j = 0; j < 3; ++j) {
            float wgt = wx[i]*wy[j];
            float dpy = (float)j - fx1;
            int cell0 = ((bi+i)*NG + (bj+j))*NG + bk;
            #pragma unroll
            for (int k = 0; k < 3; ++k) {
                float dpz = (float)k - fx2;
                float4 gv = grid[cell0 + k];
                float wgx = wgt*gv.x, wgy = wgt*gv.y, wgz = wgt*gv.z;
                nvx += wgx; nvy += wgy; nvz += wgz;
                nC[0] += wgx*dpx; nC[1] += wgx*dpy; nC[2] += wgx*dpz;
                nC[3] += wgy*dpx; nC[4] += wgy*dpy; nC[5] += wgy*dpz;
                nC[6] += wgz*dpx; nC[7] += wgz*dpy; nC[8] += wgz*dpz;
            }
        }
    }

    float* po = out + (size_t)n*25;
    float px = A0*c_DX, py = A1*c_DX, pz = A2*c_DX;   // exact reconstruction
    po[0] = px + DT*nvx;
    po[1] = py + DT*nvy;
    po[2] = pz + DT*nvz;
    po[3] = nvx; po[4] = nvy; po[5] = nvz;
    float s4 = 4.0f*c_INV_DX;
    #pragma unroll
    for (int i = 0; i < 9; ++i) po[16+i] = s4*nC[i];
}

extern "C" void kernel_launch(void* const* d_in, const int* in_sizes, int n_in,
                              void* d_out, int out_size, void* d_ws, size_t ws_size,
                              hipStream_t stream) {
    const float* x        = (const float*)d_in[0];
    const float* v        = (const float*)d_in[1];
    const float* C        = (const float*)d_in[2];
    const float* F        = (const float*)d_in[3];
    const float* Jp       = (const float*)d_in[4];
    const float* gravity  = (const float*)d_in[5];
    const float* attr_s   = (const float*)d_in[6];
    const float* attr_p   = (const float*)d_in[7];
    const int*   material = (const int*)d_in[8];
    float* out = (float*)d_out;
    int N = in_sizes[0] / 3;

    // workspace: [count G3] (zeroed) [offset G3+1][partial][rank N][grid][rec]
    char* ws = (char*)d_ws;
    size_t o = 0;
    int* cell_count = (int*)(ws + o);      o += (size_t)G3*sizeof(int);
    size_t zero_bytes = o;
    int* offset     = (int*)(ws + o);      o += ((size_t)G3+1)*sizeof(int);
    int* partial    = (int*)(ws + o);      o += (size_t)NSCAN_BLOCKS*sizeof(int);
    int* rank       = (int*)(ws + o);      o += (size_t)N*sizeof(int);
    o = (o + 127) & ~(size_t)127;
    float4* grid    = (float4*)(ws + o);   o += (size_t)G3*sizeof(float4);
    PRec* rec       = (PRec*)(ws + o);     o += (size_t)N*sizeof(PRec);

    hipMemsetAsync(d_ws, 0, zero_bytes, stream);

    int pblocks = (N + 255) / 256;
    count_kernel<<<pblocks, 256, 0, stream>>>(x, cell_count, rank, N);
    scan_partial_kernel<<<NSCAN_BLOCKS, 256, 0, stream>>>(cell_count, partial);
    scan_partials_kernel<<<1, 256, 0, stream>>>(partial);
    scan_final_kernel<<<NSCAN_BLOCKS, 256, 0, stream>>>(cell_count, partial, offset);
    pre_kernel<<<pblocks, 256, 0, stream>>>(x, v, C, F, Jp, material,
                                            offset, rank, rec, out, N);
    grid_gather_kernel<<<G3/512, 128, 0, stream>>>(rec, offset, grid,
                                                   gravity, attr_s, attr_p);
    g2p_kernel<<<pblocks, 256, 0, stream>>>(rec, grid, out, N);
}

// Round 6
// 258.840 us; speedup vs baseline: 2.1365x; 1.0069x over previous
//
#include <hip/hip_runtime.h>

#define NG 128
#define G3 (NG*NG*NG)
#define NSCAN_BLOCKS (G3/256)   // 8192

__device__ __constant__ const float c_DX      = 1.0f/128.0f;
__device__ __constant__ const float c_INV_DX  = 128.0f;

#define DT      1e-4f
#define P_VOL   ((1.0f/256.0f)*(1.0f/256.0f))
#define P_MASS  P_VOL
#define MU0     (5000.0f/(2.0f*1.2f))
#define LAM0    (5000.0f*0.2f/(1.2f*0.6f))

// 64-byte packed particle record, stored in cell-bucket order
// r0 = {A0, A1, A2, particle_id}   A = x*INV_DX (absolute grid coord; exact)
// r1 = {aff0..3}, r2 = {aff4..7}, r3 = {aff8, mv0, mv1, mv2}
struct __align__(16) PRec {
    float4 r0, r1, r2, r3;
};

// ---------------- 3x3 SVD via Jacobi on A^T A ----------------
// v6: ALL array indices compile-time (template<P,Q> rotations + register
// compare-swap sort). The previous version indexed lam[]/Vm[][] with a
// runtime sort index -> whole Vm demoted to scratch; every one of the 12
// rotations then RMW'd local memory (~1.2KB/particle scratch traffic).
template<int P, int Q>
__device__ inline void jacobi_rot(float S[3][3], float V[3][3]) {
    float apq = S[P][Q];
    if (fabsf(apq) < 1e-24f) return;
    float tau = (S[Q][Q] - S[P][P]) / (2.0f * apq);
    float t = copysignf(1.0f, tau) / (fabsf(tau) + sqrtf(1.0f + tau*tau));
    float c = rsqrtf(1.0f + t*t);
    float sn = t * c;
    #pragma unroll
    for (int k = 0; k < 3; ++k) {
        float Spk = S[P][k], Sqk = S[Q][k];
        S[P][k] = c*Spk - sn*Sqk;
        S[Q][k] = sn*Spk + c*Sqk;
    }
    #pragma unroll
    for (int k = 0; k < 3; ++k) {
        float Skp = S[k][P], Skq = S[k][Q];
        S[k][P] = c*Skp - sn*Skq;
        S[k][Q] = sn*Skp + c*Skq;
    }
    #pragma unroll
    for (int k = 0; k < 3; ++k) {
        float Vkp = V[k][P], Vkq = V[k][Q];
        V[k][P] = c*Vkp - sn*Vkq;
        V[k][Q] = sn*Vkp + c*Vkq;
    }
}

// branchless register swap (keeps everything in VGPRs)
#define CSWAPF(cond, x, y) { float _t = (x); (x) = (cond) ? (y) : (x); (y) = (cond) ? _t : (y); }

__device__ inline void svd3(const float A[9], float U[9], float sv[3], float V[9]) {
    float S[3][3];
    #pragma unroll
    for (int i = 0; i < 3; ++i)
        #pragma unroll
        for (int j = 0; j < 3; ++j) {
            float acc = 0.f;
            #pragma unroll
            for (int k = 0; k < 3; ++k) acc += A[k*3+i]*A[k*3+j];
            S[i][j] = acc;
        }
    float Vm[3][3] = {{1.f,0.f,0.f},{0.f,1.f,0.f},{0.f,0.f,1.f}};
    #pragma unroll
    for (int sweep = 0; sweep < 4; ++sweep) {
        jacobi_rot<0,1>(S, Vm);
        jacobi_rot<0,2>(S, Vm);
        jacobi_rot<1,2>(S, Vm);
    }
    // eigenvalues + eigenvector columns into named registers
    float l0 = S[0][0], l1 = S[1][1], l2 = S[2][2];
    float a0 = Vm[0][0], b0 = Vm[1][0], c0 = Vm[2][0];
    float a1 = Vm[0][1], b1 = Vm[1][1], c1 = Vm[2][1];
    float a2 = Vm[0][2], b2 = Vm[1][2], c2 = Vm[2][2];
    // descending sort; identical comparison network to the original index sort
    bool s01 = l0 < l1;
    CSWAPF(s01, l0, l1) CSWAPF(s01, a0, a1) CSWAPF(s01, b0, b1) CSWAPF(s01, c0, c1)
    bool s02 = l0 < l2;
    CSWAPF(s02, l0, l2) CSWAPF(s02, a0, a2) CSWAPF(s02, b0, b2) CSWAPF(s02, c0, c2)
    bool s12 = l1 < l2;
    CSWAPF(s12, l1, l2) CSWAPF(s12, a1, a2) CSWAPF(s12, b1, b2) CSWAPF(s12, c1, c2)

    // column 0
    {
        float l = fmaxf(l0, 0.f); float sval = sqrtf(l); sv[0] = sval;
        V[0] = a0; V[3] = b0; V[6] = c0;
        float inv = (sval > 1e-12f) ? 1.0f/sval : 0.f;
        U[0] = (A[0]*a0 + A[1]*b0 + A[2]*c0)*inv;
        U[3] = (A[3]*a0 + A[4]*b0 + A[5]*c0)*inv;
        U[6] = (A[6]*a0 + A[7]*b0 + A[8]*c0)*inv;
    }
    // column 1
    {
        float l = fmaxf(l1, 0.f); float sval = sqrtf(l); sv[1] = sval;
        V[1] = a1; V[4] = b1; V[7] = c1;
        float inv = (sval > 1e-12f) ? 1.0f/sval : 0.f;
        U[1] = (A[0]*a1 + A[1]*b1 + A[2]*c1)*inv;
        U[4] = (A[3]*a1 + A[4]*b1 + A[5]*c1)*inv;
        U[7] = (A[6]*a1 + A[7]*b1 + A[8]*c1)*inv;
    }
    // column 2
    {
        float l = fmaxf(l2, 0.f); float sval = sqrtf(l); sv[2] = sval;
        V[2] = a2; V[5] = b2; V[8] = c2;
        float inv = (sval > 1e-12f) ? 1.0f/sval : 0.f;
        U[2] = (A[0]*a2 + A[1]*b2 + A[2]*c2)*inv;
        U[5] = (A[3]*a2 + A[4]*b2 + A[5]*c2)*inv;
        U[8] = (A[6]*a2 + A[7]*b2 + A[8]*c2)*inv;
    }
}

// ---------------- binning helpers ----------------
// from absolute grid coord A: base cell + frac (all fp-exact)
__device__ inline void base_from_A(float A0, float A1, float A2,
                                   int& bi, int& bj, int& bk,
                                   float& fx0, float& fx1, float& fx2) {
    float bxf = floorf(A0 - 0.5f);
    float byf = floorf(A1 - 0.5f);
    float bzf = floorf(A2 - 0.5f);
    bi = (int)bxf; bj = (int)byf; bk = (int)bzf;
    bi = min(max(bi, 0), NG-3); bj = min(max(bj, 0), NG-3); bk = min(max(bk, 0), NG-3);
    fx0 = A0 - bxf;
    fx1 = A1 - byf;
    fx2 = A2 - bzf;
}

// count + per-particle rank within its cell (atomicAdd's return value)
__global__ void __launch_bounds__(256)
count_kernel(const float* __restrict__ x, int* __restrict__ cell_count,
             int* __restrict__ rank, int N) {
    int n = blockIdx.x*256 + threadIdx.x;
    if (n >= N) return;
    int bi, bj, bk; float f0, f1, f2;
    base_from_A(x[3*n+0]*c_INV_DX, x[3*n+1]*c_INV_DX, x[3*n+2]*c_INV_DX,
                bi, bj, bk, f0, f1, f2);
    rank[n] = atomicAdd(&cell_count[(bi*NG + bj)*NG + bk], 1);
}

// ---- scan stage A: per-block (256 elems) reduction -> partial[block] ----
__global__ void __launch_bounds__(256)
scan_partial_kernel(const int* __restrict__ count, int* __restrict__ partial) {
    __shared__ int red[256];
    int t = threadIdx.x;
    red[t] = count[blockIdx.x*256 + t];
    __syncthreads();
    for (int off = 128; off > 0; off >>= 1) {
        if (t < off) red[t] += red[t+off];
        __syncthreads();
    }
    if (t == 0) partial[blockIdx.x] = red[0];
}

// ---- scan stage B: exclusive scan of 8192 partials, 1 block, 256x32 ----
__global__ void __launch_bounds__(256)
scan_partials_kernel(int* __restrict__ partial) {
    __shared__ int part[256];
    int t = threadIdx.x;
    int base = t*32;
    int local[32];
    int s = 0;
    #pragma unroll
    for (int i = 0; i < 32; ++i) { local[i] = s; s += partial[base+i]; }
    part[t] = s;
    __syncthreads();
    for (int off = 1; off < 256; off <<= 1) {
        int v = (t >= off) ? part[t-off] : 0;
        __syncthreads();
        part[t] += v;
        __syncthreads();
    }
    int prev = (t == 0) ? 0 : part[t-1];
    #pragma unroll
    for (int i = 0; i < 32; ++i) partial[base+i] = prev + local[i];
}

// ---- scan stage C: block-level exclusive scan + partial base -> offset ----
__global__ void __launch_bounds__(256)
scan_final_kernel(const int* __restrict__ count, const int* __restrict__ partial,
                  int* __restrict__ offset) {
    __shared__ int part[256];
    int t = threadIdx.x;
    int i = blockIdx.x*256 + t;
    int c = count[i];
    part[t] = c;
    __syncthreads();
    for (int off = 1; off < 256; off <<= 1) {
        int v = (t >= off) ? part[t-off] : 0;
        __syncthreads();
        part[t] += v;
        __syncthreads();
    }
    int base = partial[blockIdx.x];
    offset[i] = base + part[t] - c;
    if (i == G3-1) offset[G3] = base + part[t];
}

// ---------------- pre-pass: all per-particle math, coalesced reads ----------------
__global__ void __launch_bounds__(256)
pre_kernel(const float* __restrict__ x, const float* __restrict__ v,
           const float* __restrict__ Cin, const float* __restrict__ Fin,
           const float* __restrict__ Jp_in, const int* __restrict__ material,
           const int* __restrict__ offset, const int* __restrict__ rank,
           PRec* __restrict__ rec, float* __restrict__ out, int N) {
    int n = blockIdx.x*256 + threadIdx.x;
    if (n >= N) return;

    float A0 = x[3*n+0]*c_INV_DX, A1 = x[3*n+1]*c_INV_DX, A2 = x[3*n+2]*c_INV_DX;
    int bi, bj, bk; float f0, f1, f2;
    base_from_A(A0, A1, A2, bi, bj, bk, f0, f1, f2);

    float Cm[9], Fm[9];
    #pragma unroll
    for (int i = 0; i < 9; ++i) { Cm[i] = Cin[9*n+i]; Fm[i] = Fin[9*n+i]; }

    // Fn = (I + DT*C) @ F
    float Fn[9];
    #pragma unroll
    for (int i = 0; i < 3; ++i)
        #pragma unroll
        for (int k = 0; k < 3; ++k) {
            float acc = Fm[i*3+k];
            #pragma unroll
            for (int j = 0; j < 3; ++j) acc += DT * Cm[i*3+j] * Fm[j*3+k];
            Fn[i*3+k] = acc;
        }

    float Jp = Jp_in[n];
    int mat = material[n];
    float h = expf(10.0f*(1.0f - Jp));
    h = fminf(fmaxf(h, 0.1f), 5.0f);
    if (mat == 1) h = 0.3f;
    float mu = (mat == 0) ? 0.0f : MU0*h;
    float la = LAM0*h;

    float U[9], V[9], sv[3];
    svd3(Fn, U, sv, V);

    float J = 1.0f;
    float sig[3];
    #pragma unroll
    for (int d = 0; d < 2; ++d) {
        float s = sv[d];
        float ns = (mat == 2) ? fminf(fmaxf(s, 1.0f-0.025f), 1.0f+0.0045f) : s;
        Jp = Jp * s / ns;
        sig[d] = ns;
        J *= ns;
    }
    sig[2] = sv[2];

    if (mat == 0) {
        float sj = sqrtf(J);
        Fn[0]=sj; Fn[1]=0; Fn[2]=0; Fn[3]=0; Fn[4]=sj; Fn[5]=0; Fn[6]=0; Fn[7]=0; Fn[8]=sj;
    } else if (mat == 2) {
        #pragma unroll
        for (int i = 0; i < 3; ++i)
            #pragma unroll
            for (int k = 0; k < 3; ++k) {
                float acc = 0.f;
                #pragma unroll
                for (int j = 0; j < 3; ++j) acc += U[i*3+j]*sig[j]*V[k*3+j];
                Fn[i*3+k] = acc;
            }
    }

    float R[9];
    #pragma unroll
    for (int i = 0; i < 3; ++i)
        #pragma unroll
        for (int k = 0; k < 3; ++k) {
            float acc = 0.f;
            #pragma unroll
            for (int j = 0; j < 3; ++j) acc += U[i*3+j]*V[k*3+j];
            R[i*3+k] = acc;
        }

    float press = la * J * (J - 1.0f);
    float scale = -DT * P_VOL * 4.0f * c_INV_DX * c_INV_DX;
    float aff[9];
    #pragma unroll
    for (int i = 0; i < 3; ++i)
        #pragma unroll
        for (int k = 0; k < 3; ++k) {
            float acc = 0.f;
            #pragma unroll
            for (int j = 0; j < 3; ++j) acc += (Fn[i*3+j]-R[i*3+j])*Fn[k*3+j];
            acc = 2.0f*mu*acc;
            if (i == k) acc += press;
            aff[i*3+k] = scale*acc + P_MASS*Cm[i*3+k];
        }

    float* po = out + (size_t)n*25;
    po[6] = Jp;
    #pragma unroll
    for (int i = 0; i < 9; ++i) po[7+i] = Fn[i];

    // cell-bucket slot (rank captured by count_kernel's atomicAdd)
    int cell = (bi*NG + bj)*NG + bk;
    int pos = offset[cell] + rank[n];

    float4* rp = (float4*)&rec[pos];
    rp[0] = make_float4(A0, A1, A2, __int_as_float(n));
    rp[1] = make_float4(aff[0], aff[1], aff[2], aff[3]);
    rp[2] = make_float4(aff[4], aff[5], aff[6], aff[7]);
    rp[3] = make_float4(aff[8], P_MASS*v[3*n+0], P_MASS*v[3*n+1], P_MASS*v[3*n+2]);
}

// ------- fused P2G-gather + grid update: one thread per 4 z-cells, NO atomics ----
// v4 (known-good 64us): single fused particle loop over all 9 (bi,bj) ranges.
//   The body is (di,dj)-independent, so the 9 ranges concatenate into ONE
//   per-lane stream: one wave-max straggler tax instead of nine.
//   Range (s,e) pairs live in LDS [range][tid] (bank = tid&31, conflict-free,
//   no barriers needed) to avoid scratch from runtime-indexed register arrays.
//   Accumulation order per cell is unchanged -> fp-identical results.
//   (round-5's 1-deep software pipeline was neutral-negative: reverted.)
__global__ void __launch_bounds__(128)
grid_gather_kernel(const PRec* __restrict__ rec, const int* __restrict__ offset,
                   float4* __restrict__ grid, const float* __restrict__ gravity,
                   const float* __restrict__ attr_s, const float* __restrict__ attr_p) {
    __shared__ int rS[9*128];
    __shared__ int rE[9*128];
    int tid = threadIdx.x;
    int g4 = blockIdx.x*128 + tid;   // quad index (G3/4 total)
    int zq = g4 & 31;
    int gj = (g4 >> 5) & (NG-1);
    int gi = g4 >> 12;
    int zlo = zq*4;

    int bk0 = max(zlo-2, 0), bk1 = min(zlo+3, NG-3);

    // fetch all 9 column ranges (18 independent loads in flight) -> LDS table
    bool any = false;
    #pragma unroll
    for (int di = 0; di < 3; ++di) {
        int bi = gi - 2 + di;
        bool vi = (bi >= 0) && (bi <= NG-3);
        #pragma unroll
        for (int dj = 0; dj < 3; ++dj) {
            int bj = gj - 2 + dj;
            bool vj = vi && (bj >= 0) && (bj <= NG-3);
            int col = ((vj ? bi : 0)*NG + (vj ? bj : 0))*NG;
            int s = vj ? offset[col + bk0]     : 0;
            int e = vj ? offset[col + bk1 + 1] : 0;
            rS[(di*3+dj)*128 + tid] = s;
            rE[(di*3+dj)*128 + tid] = e;
            if (s < e) any = true;
        }
    }

    // quads with zero visits are never read by g2p (any cell g2p reads has a
    // member particle, and member particles lie in this quad's bucket window)
    if (!any) return;

    float ax[4], ay[4], az[4], mm[4];
    #pragma unroll
    for (int h = 0; h < 4; ++h) { ax[h]=0.f; ay[h]=0.f; az[h]=0.f; mm[h]=0.f; }

    float gif = (float)gi, gjf = (float)gj, z0f = (float)zlo;

    // fused stream over the 9 ranges (per-lane private advance)
    int ridx = 0;
    int p = rS[tid], e = rE[tid];
    while (p >= e) {
        if (++ridx >= 9) break;
        p = rS[ridx*128 + tid]; e = rE[ridx*128 + tid];
    }
    while (ridx < 9) {
        const float4* rp = (const float4*)&rec[p];
        float4 r0 = rp[0];
        float4 r1 = rp[1];
        float4 r2 = rp[2];
        float4 r3 = rp[3];

        // symmetric quadratic B-spline N(u), u = cell - A (fp-exact vs ref)
        float ux = gif - r0.x;
        float aux = fabsf(ux);
        float tx = 1.5f - aux;
        float nx = (aux < 0.5f) ? (0.75f - ux*ux) : (0.5f*tx*tx);
        float uy = gjf - r0.y;
        float auy = fabsf(uy);
        float ty = 1.5f - auy;
        float ny = (auy < 0.5f) ? (0.75f - uy*uy) : (0.5f*ty*ty);
        float wgt = nx*ny;                 // reference: x,y weights only

        float uz0 = z0f - r0.z;
        float dpx = ux*c_DX, dpy = uy*c_DX, dpz0 = uz0*c_DX;
        float cx = r3.y + r1.x*dpx + r1.y*dpy + r1.z*dpz0;
        float cy = r3.z + r1.w*dpx + r2.x*dpy + r2.y*dpz0;
        float cz = r3.w + r2.z*dpx + r2.w*dpy + r3.x*dpz0;
        float ix = r1.z*c_DX, iy = r2.y*c_DX, iz = r3.x*c_DX;

        #pragma unroll
        for (int h = 0; h < 4; ++h) {
            float uz = uz0 + (float)h;
            // membership mask: uz in (-1.5, 1.5]
            float w = (uz > -1.5f && uz <= 1.5f) ? wgt : 0.f;
            ax[h] += w*cx; ay[h] += w*cy; az[h] += w*cz; mm[h] += w*P_MASS;
            cx += ix; cy += iy; cz += iz;
        }

        ++p;
        while (p >= e) {
            if (++ridx >= 9) break;
            p = rS[ridx*128 + tid]; e = rE[ridx*128 + tid];
        }
    }

    float gx = DT*gravity[0]*30.0f, gy = DT*gravity[1]*30.0f, gz = DT*gravity[2]*30.0f;
    float apx = attr_p[0], apy = attr_p[1], apz = attr_p[2];
    float as  = attr_s[0] * DT * 100.0f;

    int gidx = (gi*NG + gj)*NG + zlo;
    #pragma unroll
    for (int h = 0; h < 4; ++h) {
        float m = mm[h];
        int gk = zlo + h;
        float gvx = 0.f, gvy = 0.f, gvz = 0.f;
        if (m > 0.f) {
            float inv = 1.0f/m;
            gvx = ax[h]*inv + gx; gvy = ay[h]*inv + gy; gvz = az[h]*inv + gz;
            float dx_ = apx - c_DX*(float)gi;
            float dy_ = apy - c_DX*(float)gj;
            float dz_ = apz - c_DX*(float)gk;
            float nrm = sqrtf(dx_*dx_ + dy_*dy_ + dz_*dz_);
            float sc = as / (0.01f + nrm);
            gvx += dx_*sc; gvy += dy_*sc; gvz += dz_*sc;
            if (gi < 3      && gvx < 0.f) gvx = 0.f;
            if (gi > NG-3   && gvx > 0.f) gvx = 0.f;
            if (gj < 3      && gvy < 0.f) gvy = 0.f;
            if (gj > NG-3   && gvy > 0.f) gvy = 0.f;
            // z unconstrained (matches reference)
        }
        grid[gidx + h] = make_float4(gvx, gvy, gvz, m);
    }
}

// ---------------- G2P (cell-sorted order, coalesced record reads) ----------------
__global__ void __launch_bounds__(256)
g2p_kernel(const PRec* __restrict__ rec, const float4* __restrict__ grid,
           float* __restrict__ out, int N) {
    int gid = blockIdx.x * 256 + threadIdx.x;
    if (gid >= N) return;

    float4 r0 = rec[gid].r0;
    float A0 = r0.x, A1 = r0.y, A2 = r0.z;
    int n = __float_as_int(r0.w);

    int bi, bj, bk; float fx0, fx1, fx2;
    base_from_A(A0, A1, A2, bi, bj, bk, fx0, fx1, fx2);

    float wx[3], wy[3];
    wx[0] = 0.5f*(1.5f-fx0)*(1.5f-fx0); wx[1] = 0.75f-(fx0-1.f)*(fx0-1.f); wx[2] = 0.5f*(fx0-0.5f)*(fx0-0.5f);
    wy[0] = 0.5f*(1.5f-fx1)*(1.5f-fx1); wy[1] = 0.75f-(fx1-1.f)*(fx1-1.f); wy[2] = 0.5f*(fx1-0.5f)*(fx1-0.5f);

    float nvx = 0.f, nvy = 0.f, nvz = 0.f;
    float nC[9];
    #pragma unroll
    for (int i = 0; i < 9; ++i) nC[i] = 0.f;

    #pragma unroll
    for (int i = 0; i < 3; ++i) {
        float dpx = (float)i - fx0;
        #pragma unroll
        for (int j = 0; j < 3; ++j) {
            float wgt = wx[i]*wy[j];
            float dpy = (float)j - fx1;
            int cell0 = ((bi+i)*NG + (bj+j))*NG + bk;
            #pragma unroll
            for (int k = 0; k < 3; ++k) {
                float dpz = (float)k - fx2;
                float4 gv = grid[cell0 + k];
                float wgx = wgt*gv.x, wgy = wgt*gv.y, wgz = wgt*gv.z;
                nvx += wgx; nvy += wgy; nvz += wgz;
                nC[0] += wgx*dpx; nC[1] += wgx*dpy; nC[2] += wgx*dpz;
                nC[3] += wgy*dpx; nC[4] += wgy*dpy; nC[5] += wgy*dpz;
                nC[6] += wgz*dpx; nC[7] += wgz*dpy; nC[8] += wgz*dpz;
            }
        }
    }

    float* po = out + (size_t)n*25;
    float px = A0*c_DX, py = A1*c_DX, pz = A2*c_DX;   // exact reconstruction
    po[0] = px + DT*nvx;
    po[1] = py + DT*nvy;
    po[2] = pz + DT*nvz;
    po[3] = nvx; po[4] = nvy; po[5] = nvz;
    float s4 = 4.0f*c_INV_DX;
    #pragma unroll
    for (int i = 0; i < 9; ++i) po[16+i] = s4*nC[i];
}

extern "C" void kernel_launch(void* const* d_in, const int* in_sizes, int n_in,
                              void* d_out, int out_size, void* d_ws, size_t ws_size,
                              hipStream_t stream) {
    const float* x        = (const float*)d_in[0];
    const float* v        = (const float*)d_in[1];
    const float* C        = (const float*)d_in[2];
    const float* F        = (const float*)d_in[3];
    const float* Jp       = (const float*)d_in[4];
    const float* gravity  = (const float*)d_in[5];
    const float* attr_s   = (const float*)d_in[6];
    const float* attr_p   = (const float*)d_in[7];
    const int*   material = (const int*)d_in[8];
    float* out = (float*)d_out;
    int N = in_sizes[0] / 3;

    // workspace: [count G3] (zeroed) [offset G3+1][partial][rank N][grid][rec]
    char* ws = (char*)d_ws;
    size_t o = 0;
    int* cell_count = (int*)(ws + o);      o += (size_t)G3*sizeof(int);
    size_t zero_bytes = o;
    int* offset     = (int*)(ws + o);      o += ((size_t)G3+1)*sizeof(int);
    int* partial    = (int*)(ws + o);      o += (size_t)NSCAN_BLOCKS*sizeof(int);
    int* rank       = (int*)(ws + o);      o += (size_t)N*sizeof(int);
    o = (o + 127) & ~(size_t)127;
    float4* grid    = (float4*)(ws + o);   o += (size_t)G3*sizeof(float4);
    PRec* rec       = (PRec*)(ws + o);     o += (size_t)N*sizeof(PRec);

    hipMemsetAsync(d_ws, 0, zero_bytes, stream);

    int pblocks = (N + 255) / 256;
    count_kernel<<<pblocks, 256, 0, stream>>>(x, cell_count, rank, N);
    scan_partial_kernel<<<NSCAN_BLOCKS, 256, 0, stream>>>(cell_count, partial);
    scan_partials_kernel<<<1, 256, 0, stream>>>(partial);
    scan_final_kernel<<<NSCAN_BLOCKS, 256, 0, stream>>>(cell_count, partial, offset);
    pre_kernel<<<pblocks, 256, 0, stream>>>(x, v, C, F, Jp, material,
                                            offset, rank, rec, out, N);
    grid_gather_kernel<<<G3/512, 128, 0, stream>>>(rec, offset, grid,
                                                   gravity, attr_s, attr_p);
    g2p_kernel<<<pblocks, 256, 0, stream>>>(rec, grid, out, N);
}